// Round 1
// baseline (1121.897 us; speedup 1.0000x reference)
//
#include <hip/hip_runtime.h>

#define NN 50000
#define NE 800000

// ---------------- wave helpers ----------------
__device__ __forceinline__ float wsum64(float v) {
#pragma unroll
  for (int off = 32; off; off >>= 1) v += __shfl_xor(v, off, 64);
  return v;
}
__device__ __forceinline__ float wmax64(float v) {
#pragma unroll
  for (int off = 32; off; off >>= 1) v = fmaxf(v, __shfl_xor(v, off, 64));
  return v;
}
__device__ __forceinline__ float lrelu(float x) { return x > 0.0f ? x : 0.2f * x; }

// ---------------- CSR build ----------------
__global__ void zero_int_k(int* __restrict__ p, int n) {
  int i = blockIdx.x * 256 + threadIdx.x;
  if (i < n) p[i] = 0;
}

__global__ void count_deg_k(const int* __restrict__ dst, int* __restrict__ deg) {
  int e = blockIdx.x * 256 + threadIdx.x;
  if (e < NE) atomicAdd(&deg[dst[e]], 1);
}

__global__ __launch_bounds__(1024) void scan_k(const int* __restrict__ deg,
                                               int* __restrict__ row_ptr,
                                               int* __restrict__ cursor) {
  __shared__ int woff[16];
  int tid = threadIdx.x;
  int lane = tid & 63, wv = tid >> 6;
  const int CH = (NN + 1023) / 1024;  // 49
  int lo = tid * CH;
  int hi = lo + CH;
  if (lo > NN) lo = NN;
  if (hi > NN) hi = NN;
  int s = 0;
  for (int i = lo; i < hi; ++i) s += deg[i];
  int incl = s;
#pragma unroll
  for (int off = 1; off < 64; off <<= 1) {
    int t = __shfl_up(incl, off, 64);
    if (lane >= off) incl += t;
  }
  if (lane == 63) woff[wv] = incl;
  __syncthreads();
  if (tid == 0) {
    int run = 0;
#pragma unroll
    for (int w = 0; w < 16; ++w) { int t = woff[w]; woff[w] = run; run += t; }
    row_ptr[NN] = run;  // == NE
  }
  __syncthreads();
  int run = incl - s + woff[wv];
  for (int i = lo; i < hi; ++i) {
    row_ptr[i] = run;
    cursor[i] = run;
    run += deg[i];
  }
}

__global__ void fill_csr_k(const int* __restrict__ src, const int* __restrict__ dst,
                           int* __restrict__ cursor, int* __restrict__ csr_src) {
  int e = blockIdx.x * 256 + threadIdx.x;
  if (e < NE) {
    int pos = atomicAdd(&cursor[dst[e]], 1);
    csr_src[pos] = src[e];
  }
}

// ---------------- GEMM + el/er epilogue ----------------
// A [NN,K] * B [K,256] -> feat stored as [n][d][h] (n*256 + d*4 + h)
// el[n][h] = sum_d feat[n,h,d]*al[h,d], er likewise.
template <int K>
__global__ __launch_bounds__(256) void gemm_k(const float* __restrict__ A,
                                              const float* __restrict__ B,
                                              const float* __restrict__ al,
                                              const float* __restrict__ ar,
                                              float* __restrict__ feat,
                                              float* __restrict__ elp,
                                              float* __restrict__ erp) {
  constexpr int BK = 32;
  __shared__ float Bs[BK][256];
  __shared__ float As[32][BK];
  __shared__ float als[256], ars[256];
  int tid = threadIdx.x;
  int wave = tid >> 6, lane = tid & 63;
  int n0 = blockIdx.x * 32;
  als[tid] = al[tid];
  ars[tid] = ar[tid];
  float acc[8][4];
#pragma unroll
  for (int i = 0; i < 8; ++i)
#pragma unroll
    for (int j = 0; j < 4; ++j) acc[i][j] = 0.0f;

  for (int k0 = 0; k0 < K; k0 += BK) {
    __syncthreads();
#pragma unroll
    for (int i = 0; i < 8; ++i) {  // 32x256 floats = 2048 float4 over 256 threads
      int f = tid + i * 256;
      int kk = f >> 6, c4 = (f & 63) << 2;
      *(float4*)&Bs[kk][c4] = *(const float4*)&B[(k0 + kk) * 256 + c4];
    }
    {
      int node = tid >> 3, kk4 = (tid & 7) << 2;
      int n = n0 + node;
      float4 v = make_float4(0.0f, 0.0f, 0.0f, 0.0f);
      if (n < NN) v = *(const float4*)&A[n * K + k0 + kk4];
      *(float4*)&As[node][kk4] = v;
    }
    __syncthreads();
#pragma unroll
    for (int kk4 = 0; kk4 < BK; kk4 += 4) {
      float4 a4[8];
#pragma unroll
      for (int i = 0; i < 8; ++i) a4[i] = *(const float4*)&As[wave * 8 + i][kk4];
#pragma unroll
      for (int j = 0; j < 4; ++j) {
        int kk = kk4 + j;
        float bv0 = Bs[kk][lane];
        float bv1 = Bs[kk][64 + lane];
        float bv2 = Bs[kk][128 + lane];
        float bv3 = Bs[kk][192 + lane];
#pragma unroll
        for (int i = 0; i < 8; ++i) {
          float a = (j == 0) ? a4[i].x : (j == 1) ? a4[i].y : (j == 2) ? a4[i].z : a4[i].w;
          acc[i][0] = fmaf(a, bv0, acc[i][0]);
          acc[i][1] = fmaf(a, bv1, acc[i][1]);
          acc[i][2] = fmaf(a, bv2, acc[i][2]);
          acc[i][3] = fmaf(a, bv3, acc[i][3]);
        }
      }
    }
  }
  __syncthreads();
  float la0 = als[lane], la1 = als[64 + lane], la2 = als[128 + lane], la3 = als[192 + lane];
  float ra0 = ars[lane], ra1 = ars[64 + lane], ra2 = ars[128 + lane], ra3 = ars[192 + lane];
#pragma unroll
  for (int i = 0; i < 8; ++i) {
    int n = n0 + wave * 8 + i;
    if (n >= NN) break;
    // feat layout [n][d][h]
    *(float4*)&feat[n * 256 + (lane << 2)] =
        make_float4(acc[i][0], acc[i][1], acc[i][2], acc[i][3]);
    float e0 = wsum64(acc[i][0] * la0);
    float e1 = wsum64(acc[i][1] * la1);
    float e2 = wsum64(acc[i][2] * la2);
    float e3 = wsum64(acc[i][3] * la3);
    float r0 = wsum64(acc[i][0] * ra0);
    float r1 = wsum64(acc[i][1] * ra1);
    float r2 = wsum64(acc[i][2] * ra2);
    float r3 = wsum64(acc[i][3] * ra3);
    if (lane == 0) {
      *(float4*)&elp[n * 4] = make_float4(e0, e1, e2, e3);
      *(float4*)&erp[n * 4] = make_float4(r0, r1, r2, r3);
    }
  }
}

// ---------------- aggregation (one wave per node) ----------------
// hv[h] = (deg>0 ? acc_h/ws_h : 0) + bias[h*64+lane], for d = lane
__device__ __forceinline__ void gat_aggregate(const float* __restrict__ feat,
                                              const float* __restrict__ el,
                                              const float* __restrict__ er,
                                              const float* __restrict__ bias,
                                              const int* __restrict__ row_ptr,
                                              const int* __restrict__ csr_src,
                                              int n, int lane, float hv[4]) {
  int beg = row_ptr[n], end = row_ptr[n + 1];
  float4 er4 = *(const float4*)&er[n * 4];
  float m0 = -INFINITY, m1 = -INFINITY, m2 = -INFINITY, m3 = -INFINITY;
  for (int base = beg; base < end; base += 64) {
    int i = base + lane;
    if (i < end) {
      int s = csr_src[i];
      float4 l4 = *(const float4*)&el[s * 4];
      m0 = fmaxf(m0, lrelu(l4.x + er4.x));
      m1 = fmaxf(m1, lrelu(l4.y + er4.y));
      m2 = fmaxf(m2, lrelu(l4.z + er4.z));
      m3 = fmaxf(m3, lrelu(l4.w + er4.w));
    }
  }
  m0 = wmax64(m0); m1 = wmax64(m1); m2 = wmax64(m2); m3 = wmax64(m3);
  float a0 = 0, a1 = 0, a2 = 0, a3 = 0;
  float s0 = 0, s1 = 0, s2 = 0, s3 = 0;
  for (int base = beg; base < end; base += 64) {
    int i = base + lane;
    int cnt = min(64, end - base);
    int sl = 0;
    float w0 = 0, w1 = 0, w2 = 0, w3 = 0;
    if (i < end) {
      sl = csr_src[i];
      float4 l4 = *(const float4*)&el[sl * 4];
      w0 = __expf(lrelu(l4.x + er4.x) - m0);
      w1 = __expf(lrelu(l4.y + er4.y) - m1);
      w2 = __expf(lrelu(l4.z + er4.z) - m2);
      w3 = __expf(lrelu(l4.w + er4.w) - m3);
      s0 += w0; s1 += w1; s2 += w2; s3 += w3;
    }
    for (int j = 0; j < cnt; ++j) {
      int sj = __shfl(sl, j, 64);
      float wj0 = __shfl(w0, j, 64);
      float wj1 = __shfl(w1, j, 64);
      float wj2 = __shfl(w2, j, 64);
      float wj3 = __shfl(w3, j, 64);
      float4 f4 = *(const float4*)&feat[sj * 256 + (lane << 2)];  // [d][h] layout
      a0 = fmaf(wj0, f4.x, a0);
      a1 = fmaf(wj1, f4.y, a1);
      a2 = fmaf(wj2, f4.z, a2);
      a3 = fmaf(wj3, f4.w, a3);
    }
  }
  s0 = wsum64(s0); s1 = wsum64(s1); s2 = wsum64(s2); s3 = wsum64(s3);
  float b0 = bias[lane], b1 = bias[64 + lane], b2 = bias[128 + lane], b3 = bias[192 + lane];
  if (end > beg) {
    hv[0] = a0 / s0 + b0;
    hv[1] = a1 / s1 + b1;
    hv[2] = a2 / s2 + b2;
    hv[3] = a3 / s3 + b3;
  } else {
    hv[0] = b0; hv[1] = b1; hv[2] = b2; hv[3] = b3;
  }
}

__global__ __launch_bounds__(256) void agg_mean_k(const float* __restrict__ feat,
                                                  const float* __restrict__ el,
                                                  const float* __restrict__ er,
                                                  const float* __restrict__ bias,
                                                  const int* __restrict__ row_ptr,
                                                  const int* __restrict__ csr_src,
                                                  float* __restrict__ hout) {
  int wid = (blockIdx.x * 256 + threadIdx.x) >> 6;
  int lane = threadIdx.x & 63;
  if (wid >= NN) return;
  float hv[4];
  gat_aggregate(feat, el, er, bias, row_ptr, csr_src, wid, lane, hv);
  hout[wid * 64 + lane] = 0.25f * (hv[0] + hv[1] + hv[2] + hv[3]);
}

// last GAT layer + out_ln (Linear 256->64) + LayerNorm, fused
__global__ __launch_bounds__(256) void agg_final_k(const float* __restrict__ feat,
                                                   const float* __restrict__ el,
                                                   const float* __restrict__ er,
                                                   const float* __restrict__ bias,
                                                   const float* __restrict__ Wo,  // [256,64] (k=h*64+d major)
                                                   const float* __restrict__ bo,  // [64]
                                                   const int* __restrict__ row_ptr,
                                                   const int* __restrict__ csr_src,
                                                   float* __restrict__ out) {
  __shared__ float WoT[64][256];  // [c][ swizzled physical p=(d*4+h) ]
  __shared__ float h4s[4][256];
  int tid = threadIdx.x;
  int wave = tid >> 6, lane = tid & 63;
  // stage Wo transposed into physical layout p = d*4+h, XOR-swizzled per row c
#pragma unroll
  for (int i = 0; i < 16; ++i) {
    int f = tid + i * 256;          // float4 index over Wo (4096 total)
    int k = f >> 4;                 // logical row, k = h*64+d
    int c4 = (f & 15) << 2;
    float4 v = *(const float4*)&Wo[k * 64 + c4];
    int d = k & 63;                 // physical group index
    int h = k >> 6;                 // element within group
#pragma unroll
    for (int cc = 0; cc < 4; ++cc) {
      int c = c4 + cc;
      int g = d ^ (c & 7);          // bank swizzle
      float x = (cc == 0) ? v.x : (cc == 1) ? v.y : (cc == 2) ? v.z : v.w;
      WoT[c][(g << 2) | h] = x;
    }
  }
  __syncthreads();
  int n = blockIdx.x * 4 + wave;
  if (n >= NN) return;
  float hv[4];
  gat_aggregate(feat, el, er, bias, row_ptr, csr_src, n, lane, hv);
  *(float4*)&h4s[wave][lane << 2] = make_float4(hv[0], hv[1], hv[2], hv[3]);
  // y[c=lane] = sum_k h4[k] * Wo[k][lane] + bo[lane], over physical groups p4=d
  float y = bo[lane];
#pragma unroll
  for (int p4 = 0; p4 < 64; ++p4) {
    float4 hk = *(const float4*)&h4s[wave][p4 << 2];                 // broadcast
    float4 wk = *(const float4*)&WoT[lane][(p4 ^ (lane & 7)) << 2];  // conflict-free
    y = fmaf(hk.x, wk.x, y);
    y = fmaf(hk.y, wk.y, y);
    y = fmaf(hk.z, wk.z, y);
    y = fmaf(hk.w, wk.w, y);
  }
  // LayerNorm over 64 (no affine)
  float mu = wsum64(y) * (1.0f / 64.0f);
  float dv = y - mu;
  float var = wsum64(dv * dv) * (1.0f / 64.0f);
  out[n * 64 + lane] = dv * rsqrtf(var + 1e-5f);
}

// ---------------- launch ----------------
extern "C" void kernel_launch(void* const* d_in, const int* in_sizes, int n_in,
                              void* d_out, int out_size, void* d_ws, size_t ws_size,
                              hipStream_t stream) {
  const float* in_feat = (const float*)d_in[0];
  const int* src = (const int*)d_in[1];
  const int* dst = (const int*)d_in[2];
  const float* W1 = (const float*)d_in[3];
  const float* al1 = (const float*)d_in[4];
  const float* ar1 = (const float*)d_in[5];
  const float* b1 = (const float*)d_in[6];
  const float* Wh = (const float*)d_in[7];   // [3][64][256]
  const float* alh = (const float*)d_in[8];  // [3][4][64]
  const float* arh = (const float*)d_in[9];  // [3][4][64]
  const float* bh = (const float*)d_in[10];  // [3][256]
  const float* Wo = (const float*)d_in[11];  // [256][64]
  const float* bo = (const float*)d_in[12];  // [64]
  float* out = (float*)d_out;

  char* ws = (char*)d_ws;
  size_t off = 0;
  auto alloc = [&](size_t bytes) {
    void* p = ws + off;
    off = (off + bytes + 255) & ~(size_t)255;
    return p;
  };
  float* feat = (float*)alloc((size_t)NN * 256 * 4);
  float* el = (float*)alloc((size_t)NN * 4 * 4);
  float* er = (float*)alloc((size_t)NN * 4 * 4);
  float* h = (float*)alloc((size_t)NN * 64 * 4);
  int* deg = (int*)alloc((size_t)NN * 4);
  int* row_ptr = (int*)alloc((size_t)(NN + 1) * 4);
  int* cursor = (int*)alloc((size_t)NN * 4);
  int* csr_src = (int*)alloc((size_t)NE * 4);
  (void)ws_size; (void)in_sizes; (void)n_in; (void)out_size;

  // CSR build
  zero_int_k<<<(NN + 255) / 256, 256, 0, stream>>>(deg, NN);
  count_deg_k<<<(NE + 255) / 256, 256, 0, stream>>>(dst, deg);
  scan_k<<<1, 1024, 0, stream>>>(deg, row_ptr, cursor);
  fill_csr_k<<<(NE + 255) / 256, 256, 0, stream>>>(src, dst, cursor, csr_src);

  const int GEMM_GRID = (NN + 31) / 32;  // 1563
  const int AGG_GRID = (NN + 3) / 4;     // 12500

  // layer 1 (IN=128)
  gemm_k<128><<<GEMM_GRID, 256, 0, stream>>>(in_feat, W1, al1, ar1, feat, el, er);
  agg_mean_k<<<AGG_GRID, 256, 0, stream>>>(feat, el, er, b1, row_ptr, csr_src, h);
  // hidden layers 0,1 (mean)
  for (int i = 0; i < 2; ++i) {
    gemm_k<64><<<GEMM_GRID, 256, 0, stream>>>(h, Wh + (size_t)i * 64 * 256,
                                              alh + (size_t)i * 256, arh + (size_t)i * 256,
                                              feat, el, er);
    agg_mean_k<<<AGG_GRID, 256, 0, stream>>>(feat, el, er, bh + (size_t)i * 256,
                                             row_ptr, csr_src, h);
  }
  // last GAT layer + fused out_ln + LayerNorm
  gemm_k<64><<<GEMM_GRID, 256, 0, stream>>>(h, Wh + (size_t)2 * 64 * 256,
                                            alh + (size_t)2 * 256, arh + (size_t)2 * 256,
                                            feat, el, er);
  agg_final_k<<<AGG_GRID, 256, 0, stream>>>(feat, el, er, bh + (size_t)2 * 256, Wo, bo,
                                            row_ptr, csr_src, out);
}

// Round 2
// 1022.230 us; speedup vs baseline: 1.0975x; 1.0975x over previous
//
#include <hip/hip_runtime.h>

#define NN 50000
#define NE 800000

// ---------------- wave helpers ----------------
__device__ __forceinline__ float wsum64(float v) {
#pragma unroll
  for (int off = 32; off; off >>= 1) v += __shfl_xor(v, off, 64);
  return v;
}
__device__ __forceinline__ float wmax64(float v) {
#pragma unroll
  for (int off = 32; off; off >>= 1) v = fmaxf(v, __shfl_xor(v, off, 64));
  return v;
}
__device__ __forceinline__ float lrelu(float x) { return x > 0.0f ? x : 0.2f * x; }

// ---------------- CSR build ----------------
__global__ void zero_int_k(int* __restrict__ p, int n) {
  int i = blockIdx.x * 256 + threadIdx.x;
  if (i < n) p[i] = 0;
}

__global__ void count_deg_k(const int* __restrict__ dst, int* __restrict__ deg) {
  int e = blockIdx.x * 256 + threadIdx.x;
  if (e < NE) atomicAdd(&deg[dst[e]], 1);
}

__global__ __launch_bounds__(1024) void scan_k(const int* __restrict__ deg,
                                               int* __restrict__ row_ptr,
                                               int* __restrict__ cursor) {
  __shared__ int woff[16];
  int tid = threadIdx.x;
  int lane = tid & 63, wv = tid >> 6;
  const int CH = (NN + 1023) / 1024;  // 49
  int lo = tid * CH;
  int hi = lo + CH;
  if (lo > NN) lo = NN;
  if (hi > NN) hi = NN;
  int s = 0;
  for (int i = lo; i < hi; ++i) s += deg[i];
  int incl = s;
#pragma unroll
  for (int off = 1; off < 64; off <<= 1) {
    int t = __shfl_up(incl, off, 64);
    if (lane >= off) incl += t;
  }
  if (lane == 63) woff[wv] = incl;
  __syncthreads();
  if (tid == 0) {
    int run = 0;
#pragma unroll
    for (int w = 0; w < 16; ++w) { int t = woff[w]; woff[w] = run; run += t; }
    row_ptr[NN] = run;  // == NE
  }
  __syncthreads();
  int run = incl - s + woff[wv];
  for (int i = lo; i < hi; ++i) {
    row_ptr[i] = run;
    cursor[i] = run;
    run += deg[i];
  }
}

__global__ void fill_csr_k(const int* __restrict__ src, const int* __restrict__ dst,
                           int* __restrict__ cursor, int* __restrict__ csr_src) {
  int e = blockIdx.x * 256 + threadIdx.x;
  if (e < NE) {
    int pos = atomicAdd(&cursor[dst[e]], 1);
    csr_src[pos] = src[e];
  }
}

// ---------------- GEMM + el/er epilogue ----------------
// A [NN,K] * B [K,256] -> feat stored as [n][d][h] (n*256 + d*4 + h)
template <int K>
__global__ __launch_bounds__(256) void gemm_k(const float* __restrict__ A,
                                              const float* __restrict__ B,
                                              const float* __restrict__ al,
                                              const float* __restrict__ ar,
                                              float* __restrict__ feat,
                                              float* __restrict__ elp,
                                              float* __restrict__ erp) {
  constexpr int BK = 32;
  __shared__ float Bs[BK][256];
  __shared__ float As[32][BK];
  __shared__ float als[256], ars[256];
  int tid = threadIdx.x;
  int wave = tid >> 6, lane = tid & 63;
  int n0 = blockIdx.x * 32;
  als[tid] = al[tid];
  ars[tid] = ar[tid];
  float acc[8][4];
#pragma unroll
  for (int i = 0; i < 8; ++i)
#pragma unroll
    for (int j = 0; j < 4; ++j) acc[i][j] = 0.0f;

  for (int k0 = 0; k0 < K; k0 += BK) {
    __syncthreads();
#pragma unroll
    for (int i = 0; i < 8; ++i) {
      int f = tid + i * 256;
      int kk = f >> 6, c4 = (f & 63) << 2;
      *(float4*)&Bs[kk][c4] = *(const float4*)&B[(k0 + kk) * 256 + c4];
    }
    {
      int node = tid >> 3, kk4 = (tid & 7) << 2;
      int n = n0 + node;
      float4 v = make_float4(0.0f, 0.0f, 0.0f, 0.0f);
      if (n < NN) v = *(const float4*)&A[n * K + k0 + kk4];
      *(float4*)&As[node][kk4] = v;
    }
    __syncthreads();
#pragma unroll
    for (int kk4 = 0; kk4 < BK; kk4 += 4) {
      float4 a4[8];
#pragma unroll
      for (int i = 0; i < 8; ++i) a4[i] = *(const float4*)&As[wave * 8 + i][kk4];
#pragma unroll
      for (int j = 0; j < 4; ++j) {
        int kk = kk4 + j;
        float bv0 = Bs[kk][lane];
        float bv1 = Bs[kk][64 + lane];
        float bv2 = Bs[kk][128 + lane];
        float bv3 = Bs[kk][192 + lane];
#pragma unroll
        for (int i = 0; i < 8; ++i) {
          float a = (j == 0) ? a4[i].x : (j == 1) ? a4[i].y : (j == 2) ? a4[i].z : a4[i].w;
          acc[i][0] = fmaf(a, bv0, acc[i][0]);
          acc[i][1] = fmaf(a, bv1, acc[i][1]);
          acc[i][2] = fmaf(a, bv2, acc[i][2]);
          acc[i][3] = fmaf(a, bv3, acc[i][3]);
        }
      }
    }
  }
  __syncthreads();
  float la0 = als[lane], la1 = als[64 + lane], la2 = als[128 + lane], la3 = als[192 + lane];
  float ra0 = ars[lane], ra1 = ars[64 + lane], ra2 = ars[128 + lane], ra3 = ars[192 + lane];
#pragma unroll
  for (int i = 0; i < 8; ++i) {
    int n = n0 + wave * 8 + i;
    if (n >= NN) break;
    *(float4*)&feat[n * 256 + (lane << 2)] =
        make_float4(acc[i][0], acc[i][1], acc[i][2], acc[i][3]);
    float e0 = wsum64(acc[i][0] * la0);
    float e1 = wsum64(acc[i][1] * la1);
    float e2 = wsum64(acc[i][2] * la2);
    float e3 = wsum64(acc[i][3] * la3);
    float r0 = wsum64(acc[i][0] * ra0);
    float r1 = wsum64(acc[i][1] * ra1);
    float r2 = wsum64(acc[i][2] * ra2);
    float r3 = wsum64(acc[i][3] * ra3);
    if (lane == 0) {
      *(float4*)&elp[n * 4] = make_float4(e0, e1, e2, e3);
      *(float4*)&erp[n * 4] = make_float4(r0, r1, r2, r3);
    }
  }
}

// ---------------- aggregation core (one wave per node, scalar-uniform edges) --
// On return: a[h] = weighted feature sum for d=lane, sum[h] = softmax denom
// (identical in all lanes). sum[0] == 0 iff node has no incoming edges.
__device__ __forceinline__ void gat_node(const float* __restrict__ feat,
                                         const float* __restrict__ el,
                                         const float* __restrict__ er,
                                         const int* __restrict__ row_ptr,
                                         const int* __restrict__ csr_src,
                                         int n, int lane,
                                         float a[4], float sum[4]) {
  a[0] = a[1] = a[2] = a[3] = 0.0f;
  sum[0] = sum[1] = sum[2] = sum[3] = 0.0f;
  int beg = row_ptr[n], end = row_ptr[n + 1];
  if (end <= beg) return;
  float4 er4 = *(const float4*)&er[n * 4];
  // pass A: per-head max over incoming edges (lane-parallel gather of el)
  float m0 = -1e30f, m1 = -1e30f, m2 = -1e30f, m3 = -1e30f;
  for (int base = beg; base < end; base += 64) {
    int i = base + lane;
    if (i < end) {
      int s = csr_src[i];
      float4 l4 = *(const float4*)&el[s << 2];
      m0 = fmaxf(m0, lrelu(l4.x + er4.x));
      m1 = fmaxf(m1, lrelu(l4.y + er4.y));
      m2 = fmaxf(m2, lrelu(l4.z + er4.z));
      m3 = fmaxf(m3, lrelu(l4.w + er4.w));
    }
  }
  m0 = wmax64(m0); m1 = wmax64(m1); m2 = wmax64(m2); m3 = wmax64(m3);
  // pass B: scalar-uniform loop; all lanes compute identical weights, each lane
  // gathers its own float4 of the src feature row. Unroll 4 for MLP.
  int lane4 = lane << 2;
#define EDGE(l4, f4)                                        \
  do {                                                      \
    float w0 = __expf(lrelu(l4.x + er4.x) - m0);            \
    float w1 = __expf(lrelu(l4.y + er4.y) - m1);            \
    float w2 = __expf(lrelu(l4.z + er4.z) - m2);            \
    float w3 = __expf(lrelu(l4.w + er4.w) - m3);            \
    sum[0] += w0; sum[1] += w1; sum[2] += w2; sum[3] += w3; \
    a[0] = fmaf(w0, f4.x, a[0]);                            \
    a[1] = fmaf(w1, f4.y, a[1]);                            \
    a[2] = fmaf(w2, f4.z, a[2]);                            \
    a[3] = fmaf(w3, f4.w, a[3]);                            \
  } while (0)
  int j = beg;
  for (; j + 4 <= end; j += 4) {
    int s0 = csr_src[j], s1 = csr_src[j + 1], s2 = csr_src[j + 2], s3 = csr_src[j + 3];
    float4 lA = *(const float4*)&el[s0 << 2];
    float4 lB = *(const float4*)&el[s1 << 2];
    float4 lC = *(const float4*)&el[s2 << 2];
    float4 lD = *(const float4*)&el[s3 << 2];
    float4 fA = *(const float4*)&feat[(s0 << 8) + lane4];
    float4 fB = *(const float4*)&feat[(s1 << 8) + lane4];
    float4 fC = *(const float4*)&feat[(s2 << 8) + lane4];
    float4 fD = *(const float4*)&feat[(s3 << 8) + lane4];
    EDGE(lA, fA);
    EDGE(lB, fB);
    EDGE(lC, fC);
    EDGE(lD, fD);
  }
  for (; j < end; ++j) {
    int s0 = csr_src[j];
    float4 lA = *(const float4*)&el[s0 << 2];
    float4 fA = *(const float4*)&feat[(s0 << 8) + lane4];
    EDGE(lA, fA);
  }
#undef EDGE
}

// hidden layers: mean over heads
__global__ __launch_bounds__(256) void agg_mean_k(const float* __restrict__ feat,
                                                  const float* __restrict__ el,
                                                  const float* __restrict__ er,
                                                  const float* __restrict__ bias,
                                                  const int* __restrict__ row_ptr,
                                                  const int* __restrict__ csr_src,
                                                  float* __restrict__ hout) {
  int wid = blockIdx.x * 4 + (threadIdx.x >> 6);
  int lane = threadIdx.x & 63;
  if (wid >= NN) return;
  int n = __builtin_amdgcn_readfirstlane(wid);
  float a[4], s[4];
  gat_node(feat, el, er, row_ptr, csr_src, n, lane, a, s);
  float b0 = bias[lane], b1 = bias[64 + lane], b2 = bias[128 + lane], b3 = bias[192 + lane];
  float hv;
  if (s[0] > 0.0f)
    hv = 0.25f * ((a[0] / s[0] + b0) + (a[1] / s[1] + b1) +
                  (a[2] / s[2] + b2) + (a[3] / s[3] + b3));
  else
    hv = 0.25f * (b0 + b1 + b2 + b3);
  hout[n * 64 + lane] = hv;
}

// last GAT layer + Linear(256->64) + LayerNorm, fully fused (no LDS).
// One wave aggregates 4 nodes, then does the GEMV with coalesced Wo row loads
// shared across the 4 nodes, h4 values broadcast via uniform-index shfl.
__global__ __launch_bounds__(256) void agg_final_k(const float* __restrict__ feat,
                                                   const float* __restrict__ el,
                                                   const float* __restrict__ er,
                                                   const float* __restrict__ bias,
                                                   const float* __restrict__ Wo,  // [256,64]
                                                   const float* __restrict__ bo,  // [64]
                                                   const int* __restrict__ row_ptr,
                                                   const int* __restrict__ csr_src,
                                                   float* __restrict__ out) {
  int wave = threadIdx.x >> 6, lane = threadIdx.x & 63;
  int base = (blockIdx.x * 4 + wave) * 4;
  float b0 = bias[lane], b1 = bias[64 + lane], b2 = bias[128 + lane], b3 = bias[192 + lane];
  float hv[4][4];  // [t][h], lane holds d=lane
#pragma unroll
  for (int t = 0; t < 4; ++t) {
    int n = base + t;
    if (n < NN) {
      int nu = __builtin_amdgcn_readfirstlane(n);
      float a[4], s[4];
      gat_node(feat, el, er, row_ptr, csr_src, nu, lane, a, s);
      if (s[0] > 0.0f) {
        hv[t][0] = a[0] / s[0] + b0;
        hv[t][1] = a[1] / s[1] + b1;
        hv[t][2] = a[2] / s[2] + b2;
        hv[t][3] = a[3] / s[3] + b3;
      } else {
        hv[t][0] = b0; hv[t][1] = b1; hv[t][2] = b2; hv[t][3] = b3;
      }
    } else {
      hv[t][0] = hv[t][1] = hv[t][2] = hv[t][3] = 0.0f;
    }
  }
  // y[t][c=lane] = bo[c] + sum_{h,d} hv[t][h](lane d) * Wo[(h*64+d)*64 + c]
  float bo_l = bo[lane];
  float y0 = bo_l, y1 = bo_l, y2 = bo_l, y3 = bo_l;
#pragma unroll
  for (int h = 0; h < 4; ++h) {
#pragma unroll 4
    for (int d = 0; d < 64; ++d) {
      float wk = Wo[((h << 6) + d) * 64 + lane];  // coalesced row
      y0 = fmaf(__shfl(hv[0][h], d, 64), wk, y0);
      y1 = fmaf(__shfl(hv[1][h], d, 64), wk, y1);
      y2 = fmaf(__shfl(hv[2][h], d, 64), wk, y2);
      y3 = fmaf(__shfl(hv[3][h], d, 64), wk, y3);
    }
  }
  float ys[4] = {y0, y1, y2, y3};
#pragma unroll
  for (int t = 0; t < 4; ++t) {
    int n = base + t;
    if (n >= NN) break;
    float y = ys[t];
    float mu = wsum64(y) * (1.0f / 64.0f);
    float dv = y - mu;
    float var = wsum64(dv * dv) * (1.0f / 64.0f);
    out[n * 64 + lane] = dv * rsqrtf(var + 1e-5f);
  }
}

// ---------------- launch ----------------
extern "C" void kernel_launch(void* const* d_in, const int* in_sizes, int n_in,
                              void* d_out, int out_size, void* d_ws, size_t ws_size,
                              hipStream_t stream) {
  const float* in_feat = (const float*)d_in[0];
  const int* src = (const int*)d_in[1];
  const int* dst = (const int*)d_in[2];
  const float* W1 = (const float*)d_in[3];
  const float* al1 = (const float*)d_in[4];
  const float* ar1 = (const float*)d_in[5];
  const float* b1 = (const float*)d_in[6];
  const float* Wh = (const float*)d_in[7];   // [3][64][256]
  const float* alh = (const float*)d_in[8];  // [3][4][64]
  const float* arh = (const float*)d_in[9];  // [3][4][64]
  const float* bh = (const float*)d_in[10];  // [3][256]
  const float* Wo = (const float*)d_in[11];  // [256][64]
  const float* bo = (const float*)d_in[12];  // [64]
  float* out = (float*)d_out;

  char* ws = (char*)d_ws;
  size_t off = 0;
  auto alloc = [&](size_t bytes) {
    void* p = ws + off;
    off = (off + bytes + 255) & ~(size_t)255;
    return p;
  };
  float* feat = (float*)alloc((size_t)NN * 256 * 4);
  float* el = (float*)alloc((size_t)NN * 4 * 4);
  float* er = (float*)alloc((size_t)NN * 4 * 4);
  float* h = (float*)alloc((size_t)NN * 64 * 4);
  int* deg = (int*)alloc((size_t)NN * 4);
  int* row_ptr = (int*)alloc((size_t)(NN + 1) * 4);
  int* cursor = (int*)alloc((size_t)NN * 4);
  int* csr_src = (int*)alloc((size_t)NE * 4);
  (void)ws_size; (void)in_sizes; (void)n_in; (void)out_size;

  // CSR build
  zero_int_k<<<(NN + 255) / 256, 256, 0, stream>>>(deg, NN);
  count_deg_k<<<(NE + 255) / 256, 256, 0, stream>>>(dst, deg);
  scan_k<<<1, 1024, 0, stream>>>(deg, row_ptr, cursor);
  fill_csr_k<<<(NE + 255) / 256, 256, 0, stream>>>(src, dst, cursor, csr_src);

  const int GEMM_GRID = (NN + 31) / 32;     // 1563
  const int AGG_GRID = (NN + 3) / 4;        // 12500
  const int FINAL_GRID = (NN + 15) / 16;    // 3125

  // layer 1 (IN=128)
  gemm_k<128><<<GEMM_GRID, 256, 0, stream>>>(in_feat, W1, al1, ar1, feat, el, er);
  agg_mean_k<<<AGG_GRID, 256, 0, stream>>>(feat, el, er, b1, row_ptr, csr_src, h);
  // hidden layers 0,1 (mean)
  for (int i = 0; i < 2; ++i) {
    gemm_k<64><<<GEMM_GRID, 256, 0, stream>>>(h, Wh + (size_t)i * 64 * 256,
                                              alh + (size_t)i * 256, arh + (size_t)i * 256,
                                              feat, el, er);
    agg_mean_k<<<AGG_GRID, 256, 0, stream>>>(feat, el, er, bh + (size_t)i * 256,
                                             row_ptr, csr_src, h);
  }
  // last GAT layer + fused out_ln + LayerNorm
  gemm_k<64><<<GEMM_GRID, 256, 0, stream>>>(h, Wh + (size_t)2 * 64 * 256,
                                            alh + (size_t)2 * 256, arh + (size_t)2 * 256,
                                            feat, el, er);
  agg_final_k<<<FINAL_GRID, 256, 0, stream>>>(feat, el, er, bh + (size_t)2 * 256, Wo, bo,
                                              row_ptr, csr_src, out);
}

// Round 3
// 964.717 us; speedup vs baseline: 1.1629x; 1.0596x over previous
//
#include <hip/hip_runtime.h>

#define NN 50000
#define NE 800000

// ---------------- wave helpers ----------------
__device__ __forceinline__ float wsum64(float v) {
#pragma unroll
  for (int off = 32; off; off >>= 1) v += __shfl_xor(v, off, 64);
  return v;
}
__device__ __forceinline__ float lrelu(float x) { return x > 0.0f ? x : 0.2f * x; }

// ---------------- CSR build ----------------
__global__ void zero_int_k(int* __restrict__ p, int n) {
  int i = blockIdx.x * 256 + threadIdx.x;
  if (i < n) p[i] = 0;
}

__global__ void count_deg_k(const int* __restrict__ dst, int* __restrict__ deg) {
  int e = blockIdx.x * 256 + threadIdx.x;
  if (e < NE) atomicAdd(&deg[dst[e]], 1);
}

__global__ __launch_bounds__(1024) void scan_k(const int* __restrict__ deg,
                                               int* __restrict__ row_ptr,
                                               int* __restrict__ cursor) {
  __shared__ int woff[16];
  int tid = threadIdx.x;
  int lane = tid & 63, wv = tid >> 6;
  const int CH = (NN + 1023) / 1024;  // 49
  int lo = tid * CH;
  int hi = lo + CH;
  if (lo > NN) lo = NN;
  if (hi > NN) hi = NN;
  int s = 0;
  for (int i = lo; i < hi; ++i) s += deg[i];
  int incl = s;
#pragma unroll
  for (int off = 1; off < 64; off <<= 1) {
    int t = __shfl_up(incl, off, 64);
    if (lane >= off) incl += t;
  }
  if (lane == 63) woff[wv] = incl;
  __syncthreads();
  if (tid == 0) {
    int run = 0;
#pragma unroll
    for (int w = 0; w < 16; ++w) { int t = woff[w]; woff[w] = run; run += t; }
    row_ptr[NN] = run;  // == NE
  }
  __syncthreads();
  int run = incl - s + woff[wv];
  for (int i = lo; i < hi; ++i) {
    row_ptr[i] = run;
    cursor[i] = run;
    run += deg[i];
  }
}

__global__ void fill_csr_k(const int* __restrict__ src, const int* __restrict__ dst,
                           int* __restrict__ cursor, int* __restrict__ csr_src) {
  int e = blockIdx.x * 256 + threadIdx.x;
  if (e < NE) {
    int pos = atomicAdd(&cursor[dst[e]], 1);
    csr_src[pos] = src[e];
  }
}

// ---------------- GEMM + el/er epilogue ----------------
// A [NN,K] * B [K,256] -> feat stored as [n][d][h] (n*256 + d*4 + h)
template <int K>
__global__ __launch_bounds__(256) void gemm_k(const float* __restrict__ A,
                                              const float* __restrict__ B,
                                              const float* __restrict__ al,
                                              const float* __restrict__ ar,
                                              float* __restrict__ feat,
                                              float* __restrict__ elp,
                                              float* __restrict__ erp) {
  constexpr int BK = 32;
  __shared__ float Bs[BK][256];
  __shared__ float As[32][BK];
  __shared__ float als[256], ars[256];
  int tid = threadIdx.x;
  int wave = tid >> 6, lane = tid & 63;
  int n0 = blockIdx.x * 32;
  als[tid] = al[tid];
  ars[tid] = ar[tid];
  float acc[8][4];
#pragma unroll
  for (int i = 0; i < 8; ++i)
#pragma unroll
    for (int j = 0; j < 4; ++j) acc[i][j] = 0.0f;

  for (int k0 = 0; k0 < K; k0 += BK) {
    __syncthreads();
#pragma unroll
    for (int i = 0; i < 8; ++i) {
      int f = tid + i * 256;
      int kk = f >> 6, c4 = (f & 63) << 2;
      *(float4*)&Bs[kk][c4] = *(const float4*)&B[(k0 + kk) * 256 + c4];
    }
    {
      int node = tid >> 3, kk4 = (tid & 7) << 2;
      int n = n0 + node;
      float4 v = make_float4(0.0f, 0.0f, 0.0f, 0.0f);
      if (n < NN) v = *(const float4*)&A[n * K + k0 + kk4];
      *(float4*)&As[node][kk4] = v;
    }
    __syncthreads();
#pragma unroll
    for (int kk4 = 0; kk4 < BK; kk4 += 4) {
      float4 a4[8];
#pragma unroll
      for (int i = 0; i < 8; ++i) a4[i] = *(const float4*)&As[wave * 8 + i][kk4];
#pragma unroll
      for (int j = 0; j < 4; ++j) {
        int kk = kk4 + j;
        float bv0 = Bs[kk][lane];
        float bv1 = Bs[kk][64 + lane];
        float bv2 = Bs[kk][128 + lane];
        float bv3 = Bs[kk][192 + lane];
#pragma unroll
        for (int i = 0; i < 8; ++i) {
          float a = (j == 0) ? a4[i].x : (j == 1) ? a4[i].y : (j == 2) ? a4[i].z : a4[i].w;
          acc[i][0] = fmaf(a, bv0, acc[i][0]);
          acc[i][1] = fmaf(a, bv1, acc[i][1]);
          acc[i][2] = fmaf(a, bv2, acc[i][2]);
          acc[i][3] = fmaf(a, bv3, acc[i][3]);
        }
      }
    }
  }
  __syncthreads();
  float la0 = als[lane], la1 = als[64 + lane], la2 = als[128 + lane], la3 = als[192 + lane];
  float ra0 = ars[lane], ra1 = ars[64 + lane], ra2 = ars[128 + lane], ra3 = ars[192 + lane];
#pragma unroll
  for (int i = 0; i < 8; ++i) {
    int n = n0 + wave * 8 + i;
    if (n >= NN) break;
    *(float4*)&feat[n * 256 + (lane << 2)] =
        make_float4(acc[i][0], acc[i][1], acc[i][2], acc[i][3]);
    float e0 = wsum64(acc[i][0] * la0);
    float e1 = wsum64(acc[i][1] * la1);
    float e2 = wsum64(acc[i][2] * la2);
    float e3 = wsum64(acc[i][3] * la3);
    float r0 = wsum64(acc[i][0] * ra0);
    float r1 = wsum64(acc[i][1] * ra1);
    float r2 = wsum64(acc[i][2] * ra2);
    float r3 = wsum64(acc[i][3] * ra3);
    if (lane == 0) {
      *(float4*)&elp[n * 4] = make_float4(e0, e1, e2, e3);
      *(float4*)&erp[n * 4] = make_float4(r0, r1, r2, r3);
    }
  }
}

// ---------------- aggregation core ----------------
// Single pass, no max subtraction (|e| is O(1): exp is safe in fp32 and
// exp(e)/sum(exp(e)) === exp(e-m)/sum(exp(e-m))). All lanes compute identical
// (wave-uniform) weights; each lane gathers its own 16B of the 1KB feat row.
// Unroll 8 => 8 independent 1KB gathers in flight per wave.
__device__ __forceinline__ void gat_node(const float* __restrict__ feat,
                                         const float* __restrict__ el,
                                         const float* __restrict__ er,
                                         const int* __restrict__ row_ptr,
                                         const int* __restrict__ csr_src,
                                         int n, int lane,
                                         float a[4], float sum[4]) {
  a[0] = a[1] = a[2] = a[3] = 0.0f;
  sum[0] = sum[1] = sum[2] = sum[3] = 0.0f;
  int beg = row_ptr[n], end = row_ptr[n + 1];
  if (end <= beg) return;
  float4 er4 = *(const float4*)&er[n * 4];
  int lane4 = lane << 2;
#define EDGE(l4, f4)                                        \
  do {                                                      \
    float w0 = __expf(lrelu(l4.x + er4.x));                 \
    float w1 = __expf(lrelu(l4.y + er4.y));                 \
    float w2 = __expf(lrelu(l4.z + er4.z));                 \
    float w3 = __expf(lrelu(l4.w + er4.w));                 \
    sum[0] += w0; sum[1] += w1; sum[2] += w2; sum[3] += w3; \
    a[0] = fmaf(w0, f4.x, a[0]);                            \
    a[1] = fmaf(w1, f4.y, a[1]);                            \
    a[2] = fmaf(w2, f4.z, a[2]);                            \
    a[3] = fmaf(w3, f4.w, a[3]);                            \
  } while (0)
  int j = beg;
  for (; j + 8 <= end; j += 8) {
    int s0 = csr_src[j + 0], s1 = csr_src[j + 1];
    int s2 = csr_src[j + 2], s3 = csr_src[j + 3];
    int s4 = csr_src[j + 4], s5 = csr_src[j + 5];
    int s6 = csr_src[j + 6], s7 = csr_src[j + 7];
    float4 lA = *(const float4*)&el[s0 << 2];
    float4 lB = *(const float4*)&el[s1 << 2];
    float4 lC = *(const float4*)&el[s2 << 2];
    float4 lD = *(const float4*)&el[s3 << 2];
    float4 lE = *(const float4*)&el[s4 << 2];
    float4 lF = *(const float4*)&el[s5 << 2];
    float4 lG = *(const float4*)&el[s6 << 2];
    float4 lH = *(const float4*)&el[s7 << 2];
    float4 fA = *(const float4*)&feat[(s0 << 8) + lane4];
    float4 fB = *(const float4*)&feat[(s1 << 8) + lane4];
    float4 fC = *(const float4*)&feat[(s2 << 8) + lane4];
    float4 fD = *(const float4*)&feat[(s3 << 8) + lane4];
    float4 fE = *(const float4*)&feat[(s4 << 8) + lane4];
    float4 fF = *(const float4*)&feat[(s5 << 8) + lane4];
    float4 fG = *(const float4*)&feat[(s6 << 8) + lane4];
    float4 fH = *(const float4*)&feat[(s7 << 8) + lane4];
    EDGE(lA, fA); EDGE(lB, fB); EDGE(lC, fC); EDGE(lD, fD);
    EDGE(lE, fE); EDGE(lF, fF); EDGE(lG, fG); EDGE(lH, fH);
  }
  for (; j < end; ++j) {
    int s0 = csr_src[j];
    float4 lA = *(const float4*)&el[s0 << 2];
    float4 fA = *(const float4*)&feat[(s0 << 8) + lane4];
    EDGE(lA, fA);
  }
#undef EDGE
}

// hidden layers: mean over heads
__global__ __launch_bounds__(256) void agg_mean_k(const float* __restrict__ feat,
                                                  const float* __restrict__ el,
                                                  const float* __restrict__ er,
                                                  const float* __restrict__ bias,
                                                  const int* __restrict__ row_ptr,
                                                  const int* __restrict__ csr_src,
                                                  float* __restrict__ hout) {
  int wid = blockIdx.x * 4 + (threadIdx.x >> 6);
  int lane = threadIdx.x & 63;
  if (wid >= NN) return;
  int n = __builtin_amdgcn_readfirstlane(wid);
  float a[4], s[4];
  gat_node(feat, el, er, row_ptr, csr_src, n, lane, a, s);
  float b0 = bias[lane], b1 = bias[64 + lane], b2 = bias[128 + lane], b3 = bias[192 + lane];
  float hv;
  if (s[0] > 0.0f)
    hv = 0.25f * ((a[0] / s[0] + b0) + (a[1] / s[1] + b1) +
                  (a[2] / s[2] + b2) + (a[3] / s[3] + b3));
  else
    hv = 0.25f * (b0 + b1 + b2 + b3);
  hout[n * 64 + lane] = hv;
}

// last GAT layer + Linear(256->64) + LayerNorm, fully fused (no LDS).
__global__ __launch_bounds__(256) void agg_final_k(const float* __restrict__ feat,
                                                   const float* __restrict__ el,
                                                   const float* __restrict__ er,
                                                   const float* __restrict__ bias,
                                                   const float* __restrict__ Wo,  // [256,64]
                                                   const float* __restrict__ bo,  // [64]
                                                   const int* __restrict__ row_ptr,
                                                   const int* __restrict__ csr_src,
                                                   float* __restrict__ out) {
  int wave = threadIdx.x >> 6, lane = threadIdx.x & 63;
  int base = (blockIdx.x * 4 + wave) * 4;
  float b0 = bias[lane], b1 = bias[64 + lane], b2 = bias[128 + lane], b3 = bias[192 + lane];
  float hv[4][4];  // [t][h], lane holds d=lane
#pragma unroll
  for (int t = 0; t < 4; ++t) {
    int n = base + t;
    if (n < NN) {
      int nu = __builtin_amdgcn_readfirstlane(n);
      float a[4], s[4];
      gat_node(feat, el, er, row_ptr, csr_src, nu, lane, a, s);
      if (s[0] > 0.0f) {
        hv[t][0] = a[0] / s[0] + b0;
        hv[t][1] = a[1] / s[1] + b1;
        hv[t][2] = a[2] / s[2] + b2;
        hv[t][3] = a[3] / s[3] + b3;
      } else {
        hv[t][0] = b0; hv[t][1] = b1; hv[t][2] = b2; hv[t][3] = b3;
      }
    } else {
      hv[t][0] = hv[t][1] = hv[t][2] = hv[t][3] = 0.0f;
    }
  }
  // y[t][c=lane] = bo[c] + sum_{h,d} hv[t][h](lane d) * Wo[(h*64+d)*64 + c]
  float bo_l = bo[lane];
  float y0 = bo_l, y1 = bo_l, y2 = bo_l, y3 = bo_l;
#pragma unroll
  for (int h = 0; h < 4; ++h) {
#pragma unroll 4
    for (int d = 0; d < 64; ++d) {
      float wk = Wo[((h << 6) + d) * 64 + lane];  // coalesced row, L2-hot
      y0 = fmaf(__shfl(hv[0][h], d, 64), wk, y0);
      y1 = fmaf(__shfl(hv[1][h], d, 64), wk, y1);
      y2 = fmaf(__shfl(hv[2][h], d, 64), wk, y2);
      y3 = fmaf(__shfl(hv[3][h], d, 64), wk, y3);
    }
  }
  float ys[4] = {y0, y1, y2, y3};
#pragma unroll
  for (int t = 0; t < 4; ++t) {
    int n = base + t;
    if (n >= NN) break;
    float y = ys[t];
    float mu = wsum64(y) * (1.0f / 64.0f);
    float dv = y - mu;
    float var = wsum64(dv * dv) * (1.0f / 64.0f);
    out[n * 64 + lane] = dv * rsqrtf(var + 1e-5f);
  }
}

// ---------------- launch ----------------
extern "C" void kernel_launch(void* const* d_in, const int* in_sizes, int n_in,
                              void* d_out, int out_size, void* d_ws, size_t ws_size,
                              hipStream_t stream) {
  const float* in_feat = (const float*)d_in[0];
  const int* src = (const int*)d_in[1];
  const int* dst = (const int*)d_in[2];
  const float* W1 = (const float*)d_in[3];
  const float* al1 = (const float*)d_in[4];
  const float* ar1 = (const float*)d_in[5];
  const float* b1 = (const float*)d_in[6];
  const float* Wh = (const float*)d_in[7];   // [3][64][256]
  const float* alh = (const float*)d_in[8];  // [3][4][64]
  const float* arh = (const float*)d_in[9];  // [3][4][64]
  const float* bh = (const float*)d_in[10];  // [3][256]
  const float* Wo = (const float*)d_in[11];  // [256][64]
  const float* bo = (const float*)d_in[12];  // [64]
  float* out = (float*)d_out;

  char* ws = (char*)d_ws;
  size_t off = 0;
  auto alloc = [&](size_t bytes) {
    void* p = ws + off;
    off = (off + bytes + 255) & ~(size_t)255;
    return p;
  };
  float* feat = (float*)alloc((size_t)NN * 256 * 4);
  float* el = (float*)alloc((size_t)NN * 4 * 4);
  float* er = (float*)alloc((size_t)NN * 4 * 4);
  float* h = (float*)alloc((size_t)NN * 64 * 4);
  int* deg = (int*)alloc((size_t)NN * 4);
  int* row_ptr = (int*)alloc((size_t)(NN + 1) * 4);
  int* cursor = (int*)alloc((size_t)NN * 4);
  int* csr_src = (int*)alloc((size_t)NE * 4);
  (void)ws_size; (void)in_sizes; (void)n_in; (void)out_size;

  // CSR build
  zero_int_k<<<(NN + 255) / 256, 256, 0, stream>>>(deg, NN);
  count_deg_k<<<(NE + 255) / 256, 256, 0, stream>>>(dst, deg);
  scan_k<<<1, 1024, 0, stream>>>(deg, row_ptr, cursor);
  fill_csr_k<<<(NE + 255) / 256, 256, 0, stream>>>(src, dst, cursor, csr_src);

  const int GEMM_GRID = (NN + 31) / 32;     // 1563
  const int AGG_GRID = (NN + 3) / 4;        // 12500
  const int FINAL_GRID = (NN + 15) / 16;    // 3125

  // layer 1 (IN=128)
  gemm_k<128><<<GEMM_GRID, 256, 0, stream>>>(in_feat, W1, al1, ar1, feat, el, er);
  agg_mean_k<<<AGG_GRID, 256, 0, stream>>>(feat, el, er, b1, row_ptr, csr_src, h);
  // hidden layers 0,1 (mean)
  for (int i = 0; i < 2; ++i) {
    gemm_k<64><<<GEMM_GRID, 256, 0, stream>>>(h, Wh + (size_t)i * 64 * 256,
                                              alh + (size_t)i * 256, arh + (size_t)i * 256,
                                              feat, el, er);
    agg_mean_k<<<AGG_GRID, 256, 0, stream>>>(feat, el, er, bh + (size_t)i * 256,
                                             row_ptr, csr_src, h);
  }
  // last GAT layer + fused out_ln + LayerNorm
  gemm_k<64><<<GEMM_GRID, 256, 0, stream>>>(h, Wh + (size_t)2 * 64 * 256,
                                            alh + (size_t)2 * 256, arh + (size_t)2 * 256,
                                            feat, el, er);
  agg_final_k<<<FINAL_GRID, 256, 0, stream>>>(feat, el, er, bh + (size_t)2 * 256, Wo, bo,
                                              row_ptr, csr_src, out);
}

// Round 4
// 859.964 us; speedup vs baseline: 1.3046x; 1.1218x over previous
//
#include <hip/hip_runtime.h>

#define NN 50000
#define NE 800000

// ---------------- wave helpers ----------------
__device__ __forceinline__ float wsum64(float v) {
#pragma unroll
  for (int off = 32; off; off >>= 1) v += __shfl_xor(v, off, 64);
  return v;
}
__device__ __forceinline__ float lrelu(float x) { return x > 0.0f ? x : 0.2f * x; }

// ---------------- CSR build ----------------
__global__ void zero_int_k(int* __restrict__ p, int n) {
  int i = blockIdx.x * 256 + threadIdx.x;
  if (i < n) p[i] = 0;
}

__global__ void count_deg_k(const int* __restrict__ dst, int* __restrict__ deg) {
  int e = blockIdx.x * 256 + threadIdx.x;
  if (e < NE) atomicAdd(&deg[dst[e]], 1);
}

__global__ __launch_bounds__(1024) void scan_k(const int* __restrict__ deg,
                                               int* __restrict__ row_ptr,
                                               int* __restrict__ cursor) {
  __shared__ int woff[16];
  int tid = threadIdx.x;
  int lane = tid & 63, wv = tid >> 6;
  const int CH = (NN + 1023) / 1024;  // 49
  int lo = tid * CH;
  int hi = lo + CH;
  if (lo > NN) lo = NN;
  if (hi > NN) hi = NN;
  int s = 0;
  for (int i = lo; i < hi; ++i) s += deg[i];
  int incl = s;
#pragma unroll
  for (int off = 1; off < 64; off <<= 1) {
    int t = __shfl_up(incl, off, 64);
    if (lane >= off) incl += t;
  }
  if (lane == 63) woff[wv] = incl;
  __syncthreads();
  if (tid == 0) {
    int run = 0;
#pragma unroll
    for (int w = 0; w < 16; ++w) { int t = woff[w]; woff[w] = run; run += t; }
    row_ptr[NN] = run;  // == NE
  }
  __syncthreads();
  int run = incl - s + woff[wv];
  for (int i = lo; i < hi; ++i) {
    row_ptr[i] = run;
    cursor[i] = run;
    run += deg[i];
  }
}

__global__ void fill_csr_k(const int* __restrict__ src, const int* __restrict__ dst,
                           int* __restrict__ cursor, int* __restrict__ csr_src) {
  int e = blockIdx.x * 256 + threadIdx.x;
  if (e < NE) {
    int pos = atomicAdd(&cursor[dst[e]], 1);
    csr_src[pos] = src[e];
  }
}

// ---------------- tiny precomputes ----------------
// Q[k][c] for c in 0..7: c<4 -> el proj head c, c>=4 -> er proj head c-4
// Q[k][h]   = sum_m W[k][h*64+m]*al[h][m]
__global__ void compute_q_k(const float* __restrict__ W, const float* __restrict__ al,
                            const float* __restrict__ ar, float* __restrict__ Q, int KDIM) {
  int idx = blockIdx.x * 256 + threadIdx.x;
  if (idx >= KDIM * 8) return;
  int k = idx >> 3, c = idx & 7;
  int h = c & 3;
  const float* av = (c < 4 ? al : ar) + h * 64;
  const float* wrow = W + (size_t)k * 256 + h * 64;
  float s = 0.0f;
  for (int m = 0; m < 64; ++m) s += wrow[m] * av[m];
  Q[idx] = s;
}

// M[(h*64+k)][d] = sum_j Wh2[k][h*64+j] * Wo[(h*64+j)][d]
__global__ void compute_m_k(const float* __restrict__ Wh2, const float* __restrict__ Wo,
                            float* __restrict__ M) {
  int row = blockIdx.x;     // 0..255
  int d = threadIdx.x;      // 0..63
  int h = row >> 6, k = row & 63;
  float s = 0.0f;
  for (int j = 0; j < 64; ++j)
    s += Wh2[k * 256 + h * 64 + j] * Wo[(h * 64 + j) * 64 + d];
  M[row * 64 + d] = s;
}

// cvec[d] = sum_m bh2[m]*Wo[m][d] + bo[d]
__global__ void compute_c_k(const float* __restrict__ bh2, const float* __restrict__ Wo,
                            const float* __restrict__ bo, float* __restrict__ cvec) {
  int d = threadIdx.x;
  if (d >= 64) return;
  float s = bo[d];
  for (int m = 0; m < 256; ++m) s += bh2[m] * Wo[m * 64 + d];
  cvec[d] = s;
}

// ---------------- el/er for layer 1 (from raw inputs) ----------------
template <int KD>
__global__ __launch_bounds__(256) void eler_k(const float* __restrict__ X,
                                              const float* __restrict__ Q,
                                              float* __restrict__ elp,
                                              float* __restrict__ erp) {
  int n = __builtin_amdgcn_readfirstlane(blockIdx.x * 4 + (threadIdx.x >> 6));
  int lane = threadIdx.x & 63;
  float p[8];
  if constexpr (KD == 64) {
    float xv = X[(n << 6) + lane];
    float4 qa = *(const float4*)&Q[lane * 8];
    float4 qb = *(const float4*)&Q[lane * 8 + 4];
    p[0] = xv * qa.x; p[1] = xv * qa.y; p[2] = xv * qa.z; p[3] = xv * qa.w;
    p[4] = xv * qb.x; p[5] = xv * qb.y; p[6] = xv * qb.z; p[7] = xv * qb.w;
  } else {
    float2 xv = *(const float2*)&X[(n << 7) + (lane << 1)];
    float4 qa0 = *(const float4*)&Q[(lane * 2) * 8];
    float4 qb0 = *(const float4*)&Q[(lane * 2) * 8 + 4];
    float4 qa1 = *(const float4*)&Q[(lane * 2 + 1) * 8];
    float4 qb1 = *(const float4*)&Q[(lane * 2 + 1) * 8 + 4];
    p[0] = xv.x * qa0.x + xv.y * qa1.x; p[1] = xv.x * qa0.y + xv.y * qa1.y;
    p[2] = xv.x * qa0.z + xv.y * qa1.z; p[3] = xv.x * qa0.w + xv.y * qa1.w;
    p[4] = xv.x * qb0.x + xv.y * qb1.x; p[5] = xv.x * qb0.y + xv.y * qb1.y;
    p[6] = xv.x * qb0.z + xv.y * qb1.z; p[7] = xv.x * qb0.w + xv.y * qb1.w;
  }
#pragma unroll
  for (int c = 0; c < 8; ++c) p[c] = wsum64(p[c]);
  if (lane == 0) {
    *(float4*)&elp[n << 2] = make_float4(p[0], p[1], p[2], p[3]);
    *(float4*)&erp[n << 2] = make_float4(p[4], p[5], p[6], p[7]);
  }
}

// ---------------- aggregation helpers ----------------
struct Acc {
  float4 a0, a1, a2, a3;
  float s0, s1, s2, s3;
};

__device__ __forceinline__ void edge_acc(const float4& l4, const float4& f4,
                                         const float4& er4, Acc& A, float mask) {
  float w0 = __expf(lrelu(l4.x + er4.x)) * mask;
  float w1 = __expf(lrelu(l4.y + er4.y)) * mask;
  float w2 = __expf(lrelu(l4.z + er4.z)) * mask;
  float w3 = __expf(lrelu(l4.w + er4.w)) * mask;
  A.s0 += w0; A.s1 += w1; A.s2 += w2; A.s3 += w3;
  A.a0.x = fmaf(w0, f4.x, A.a0.x); A.a0.y = fmaf(w0, f4.y, A.a0.y);
  A.a0.z = fmaf(w0, f4.z, A.a0.z); A.a0.w = fmaf(w0, f4.w, A.a0.w);
  A.a1.x = fmaf(w1, f4.x, A.a1.x); A.a1.y = fmaf(w1, f4.y, A.a1.y);
  A.a1.z = fmaf(w1, f4.z, A.a1.z); A.a1.w = fmaf(w1, f4.w, A.a1.w);
  A.a2.x = fmaf(w2, f4.x, A.a2.x); A.a2.y = fmaf(w2, f4.y, A.a2.y);
  A.a2.z = fmaf(w2, f4.z, A.a2.z); A.a2.w = fmaf(w2, f4.w, A.a2.w);
  A.a3.x = fmaf(w3, f4.x, A.a3.x); A.a3.y = fmaf(w3, f4.y, A.a3.y);
  A.a3.z = fmaf(w3, f4.z, A.a3.z); A.a3.w = fmaf(w3, f4.w, A.a3.w);
}

template <int FIRST>
__device__ __forceinline__ void reduce_acc(Acc& A) {
#pragma unroll
  for (int m = FIRST; m <= 32; m <<= 1) {
    A.a0.x += __shfl_xor(A.a0.x, m, 64); A.a0.y += __shfl_xor(A.a0.y, m, 64);
    A.a0.z += __shfl_xor(A.a0.z, m, 64); A.a0.w += __shfl_xor(A.a0.w, m, 64);
    A.a1.x += __shfl_xor(A.a1.x, m, 64); A.a1.y += __shfl_xor(A.a1.y, m, 64);
    A.a1.z += __shfl_xor(A.a1.z, m, 64); A.a1.w += __shfl_xor(A.a1.w, m, 64);
    A.a2.x += __shfl_xor(A.a2.x, m, 64); A.a2.y += __shfl_xor(A.a2.y, m, 64);
    A.a2.z += __shfl_xor(A.a2.z, m, 64); A.a2.w += __shfl_xor(A.a2.w, m, 64);
    A.a3.x += __shfl_xor(A.a3.x, m, 64); A.a3.y += __shfl_xor(A.a3.y, m, 64);
    A.a3.z += __shfl_xor(A.a3.z, m, 64); A.a3.w += __shfl_xor(A.a3.w, m, 64);
    A.s0 += __shfl_xor(A.s0, m, 64); A.s1 += __shfl_xor(A.s1, m, 64);
    A.s2 += __shfl_xor(A.s2, m, 64); A.s3 += __shfl_xor(A.s3, m, 64);
  }
}

// aggregate node n over x rows of dim 64; quarter-wave per edge.
__device__ __forceinline__ void agg64(const float* __restrict__ x,
                                      const float* __restrict__ el,
                                      const float* __restrict__ er,
                                      const int* __restrict__ row_ptr,
                                      const int* __restrict__ csr_src,
                                      int n, int q, int r, Acc& A) {
  A.a0 = A.a1 = A.a2 = A.a3 = make_float4(0.f, 0.f, 0.f, 0.f);
  A.s0 = A.s1 = A.s2 = A.s3 = 0.f;
  int beg = row_ptr[n], end = row_ptr[n + 1];
  if (end > beg) {
    float4 er4 = *(const float4*)&er[n << 2];
    int r4 = r << 2;
    int j = beg;
    for (; j + 16 <= end; j += 16) {
      int sA = csr_src[j + q],      sB = csr_src[j + 4 + q];
      int sC = csr_src[j + 8 + q],  sD = csr_src[j + 12 + q];
      float4 lA = *(const float4*)&el[sA << 2];
      float4 lB = *(const float4*)&el[sB << 2];
      float4 lC = *(const float4*)&el[sC << 2];
      float4 lD = *(const float4*)&el[sD << 2];
      float4 fA = *(const float4*)&x[(sA << 6) + r4];
      float4 fB = *(const float4*)&x[(sB << 6) + r4];
      float4 fC = *(const float4*)&x[(sC << 6) + r4];
      float4 fD = *(const float4*)&x[(sD << 6) + r4];
      edge_acc(lA, fA, er4, A, 1.0f);
      edge_acc(lB, fB, er4, A, 1.0f);
      edge_acc(lC, fC, er4, A, 1.0f);
      edge_acc(lD, fD, er4, A, 1.0f);
    }
    for (; j < end; j += 4) {
      int e = j + q;
      int ee = min(e, end - 1);
      int sA = csr_src[ee];
      float4 lA = *(const float4*)&el[sA << 2];
      float4 fA = *(const float4*)&x[(sA << 6) + r4];
      edge_acc(lA, fA, er4, A, (e < end) ? 1.0f : 0.0f);
    }
  }
  reduce_acc<16>(A);
}

// ---------------- fused layer kernels ----------------
// hidden: aggregate x (dim64) -> g, GEMV vs W (S remap, *0.25) + mean-bias,
// write h, next-layer el/er epilogue.
__global__ __launch_bounds__(256) void fused_hidden_k(
    const float* __restrict__ x, const float* __restrict__ el,
    const float* __restrict__ er, const float* __restrict__ W,
    const float* __restrict__ b, const float* __restrict__ Qn,
    const int* __restrict__ row_ptr, const int* __restrict__ csr_src,
    float* __restrict__ hout, float* __restrict__ eln, float* __restrict__ ern) {
  __shared__ float gs[4 * 4 * 256];
  int wave = threadIdx.x >> 6, lane = threadIdx.x & 63;
  int q = lane >> 4, r = lane & 15;
  int base = (blockIdx.x * 4 + wave) * 4;
  float* gw = &gs[wave * 1024];
#pragma unroll
  for (int t = 0; t < 4; ++t) {
    int n = __builtin_amdgcn_readfirstlane(base + t);
    Acc A;
    agg64(x, el, er, row_ptr, csr_src, n, q, r, A);
    float inv0 = A.s0 > 0.f ? 1.0f / A.s0 : 0.f;
    float inv1 = A.s1 > 0.f ? 1.0f / A.s1 : 0.f;
    float inv2 = A.s2 > 0.f ? 1.0f / A.s2 : 0.f;
    float inv3 = A.s3 > 0.f ? 1.0f / A.s3 : 0.f;
    float4 av = (q == 0) ? A.a0 : (q == 1) ? A.a1 : (q == 2) ? A.a2 : A.a3;
    float inv = (q == 0) ? inv0 : (q == 1) ? inv1 : (q == 2) ? inv2 : inv3;
    av.x *= inv; av.y *= inv; av.z *= inv; av.w *= inv;
    *(float4*)&gw[t * 256 + (q << 6) + (r << 2)] = av;
  }
  // GEMV: y[t][lane] = sum_rr g[t][rr] * W[k][h*64+lane], rr=h*64+k
  float y0 = 0.f, y1 = 0.f, y2 = 0.f, y3 = 0.f;
  for (int rr = 0; rr < 256; rr += 4) {
#pragma unroll
    for (int u = 0; u < 4; ++u) {
      int row = rr + u;
      int h = row >> 6, k = row & 63;
      float sv = W[k * 256 + (h << 6) + lane];
      float g0 = gw[0 * 256 + row], g1 = gw[1 * 256 + row];
      float g2 = gw[2 * 256 + row], g3 = gw[3 * 256 + row];
      y0 = fmaf(g0, sv, y0); y1 = fmaf(g1, sv, y1);
      y2 = fmaf(g2, sv, y2); y3 = fmaf(g3, sv, y3);
    }
  }
  float bsum = b[lane] + b[64 + lane] + b[128 + lane] + b[192 + lane];
  float4 qa = *(const float4*)&Qn[lane * 8];
  float4 qb = *(const float4*)&Qn[lane * 8 + 4];
  float ys[4] = {y0, y1, y2, y3};
#pragma unroll
  for (int t = 0; t < 4; ++t) {
    int n = base + t;
    float yv = 0.25f * (ys[t] + bsum);
    hout[(n << 6) + lane] = yv;
    float e0 = wsum64(yv * qa.x), e1 = wsum64(yv * qa.y);
    float e2 = wsum64(yv * qa.z), e3 = wsum64(yv * qa.w);
    float r0 = wsum64(yv * qb.x), r1 = wsum64(yv * qb.y);
    float r2 = wsum64(yv * qb.z), r3 = wsum64(yv * qb.w);
    if (lane == 0) {
      *(float4*)&eln[n << 2] = make_float4(e0, e1, e2, e3);
      *(float4*)&ern[n << 2] = make_float4(r0, r1, r2, r3);
    }
  }
}

// layer 1: aggregate in_feat (dim128), half-wave per edge.
__global__ __launch_bounds__(256) void fused_l1_k(
    const float* __restrict__ x, const float* __restrict__ el,
    const float* __restrict__ er, const float* __restrict__ W,
    const float* __restrict__ b, const float* __restrict__ Qn,
    const int* __restrict__ row_ptr, const int* __restrict__ csr_src,
    float* __restrict__ hout, float* __restrict__ eln, float* __restrict__ ern) {
  __shared__ float gs[4 * 4 * 512];
  int wave = threadIdx.x >> 6, lane = threadIdx.x & 63;
  int q = lane >> 5, r = lane & 31;  // half-wave per edge
  int base = (blockIdx.x * 4 + wave) * 4;
  float* gw = &gs[wave * 2048];
#pragma unroll
  for (int t = 0; t < 4; ++t) {
    int n = __builtin_amdgcn_readfirstlane(base + t);
    Acc A;
    A.a0 = A.a1 = A.a2 = A.a3 = make_float4(0.f, 0.f, 0.f, 0.f);
    A.s0 = A.s1 = A.s2 = A.s3 = 0.f;
    int beg = row_ptr[n], end = row_ptr[n + 1];
    if (end > beg) {
      float4 er4 = *(const float4*)&er[n << 2];
      int r4 = r << 2;
      int j = beg;
      for (; j + 8 <= end; j += 8) {
        int sA = csr_src[j + q],     sB = csr_src[j + 2 + q];
        int sC = csr_src[j + 4 + q], sD = csr_src[j + 6 + q];
        float4 lA = *(const float4*)&el[sA << 2];
        float4 lB = *(const float4*)&el[sB << 2];
        float4 lC = *(const float4*)&el[sC << 2];
        float4 lD = *(const float4*)&el[sD << 2];
        float4 fA = *(const float4*)&x[(sA << 7) + r4];
        float4 fB = *(const float4*)&x[(sB << 7) + r4];
        float4 fC = *(const float4*)&x[(sC << 7) + r4];
        float4 fD = *(const float4*)&x[(sD << 7) + r4];
        edge_acc(lA, fA, er4, A, 1.0f);
        edge_acc(lB, fB, er4, A, 1.0f);
        edge_acc(lC, fC, er4, A, 1.0f);
        edge_acc(lD, fD, er4, A, 1.0f);
      }
      for (; j < end; j += 2) {
        int e = j + q;
        int ee = min(e, end - 1);
        int sA = csr_src[ee];
        float4 lA = *(const float4*)&el[sA << 2];
        float4 fA = *(const float4*)&x[(sA << 7) + r4];
        edge_acc(lA, fA, er4, A, (e < end) ? 1.0f : 0.0f);
      }
    }
    reduce_acc<32>(A);
    float inv0 = A.s0 > 0.f ? 1.0f / A.s0 : 0.f;
    float inv1 = A.s1 > 0.f ? 1.0f / A.s1 : 0.f;
    float inv2 = A.s2 > 0.f ? 1.0f / A.s2 : 0.f;
    float inv3 = A.s3 > 0.f ? 1.0f / A.s3 : 0.f;
    int r4 = r << 2;
    *(float4*)&gw[t * 512 + 0 * 128 + r4] =
        make_float4(A.a0.x * inv0, A.a0.y * inv0, A.a0.z * inv0, A.a0.w * inv0);
    *(float4*)&gw[t * 512 + 1 * 128 + r4] =
        make_float4(A.a1.x * inv1, A.a1.y * inv1, A.a1.z * inv1, A.a1.w * inv1);
    *(float4*)&gw[t * 512 + 2 * 128 + r4] =
        make_float4(A.a2.x * inv2, A.a2.y * inv2, A.a2.z * inv2, A.a2.w * inv2);
    *(float4*)&gw[t * 512 + 3 * 128 + r4] =
        make_float4(A.a3.x * inv3, A.a3.y * inv3, A.a3.z * inv3, A.a3.w * inv3);
  }
  float y0 = 0.f, y1 = 0.f, y2 = 0.f, y3 = 0.f;
  for (int rr = 0; rr < 512; rr += 4) {
#pragma unroll
    for (int u = 0; u < 4; ++u) {
      int row = rr + u;
      int h = row >> 7, k = row & 127;
      float sv = W[k * 256 + (h << 6) + lane];
      float g0 = gw[0 * 512 + row], g1 = gw[1 * 512 + row];
      float g2 = gw[2 * 512 + row], g3 = gw[3 * 512 + row];
      y0 = fmaf(g0, sv, y0); y1 = fmaf(g1, sv, y1);
      y2 = fmaf(g2, sv, y2); y3 = fmaf(g3, sv, y3);
    }
  }
  float bsum = b[lane] + b[64 + lane] + b[128 + lane] + b[192 + lane];
  float4 qa = *(const float4*)&Qn[lane * 8];
  float4 qb = *(const float4*)&Qn[lane * 8 + 4];
  float ys[4] = {y0, y1, y2, y3};
#pragma unroll
  for (int t = 0; t < 4; ++t) {
    int n = base + t;
    float yv = 0.25f * (ys[t] + bsum);
    hout[(n << 6) + lane] = yv;
    float e0 = wsum64(yv * qa.x), e1 = wsum64(yv * qa.y);
    float e2 = wsum64(yv * qa.z), e3 = wsum64(yv * qa.w);
    float r0 = wsum64(yv * qb.x), r1 = wsum64(yv * qb.y);
    float r2 = wsum64(yv * qb.z), r3 = wsum64(yv * qb.w);
    if (lane == 0) {
      *(float4*)&eln[n << 2] = make_float4(e0, e1, e2, e3);
      *(float4*)&ern[n << 2] = make_float4(r0, r1, r2, r3);
    }
  }
}

// final: aggregate h3 -> g, GEMV vs M + cvec, LayerNorm -> out
__global__ __launch_bounds__(256) void fused_final_k(
    const float* __restrict__ x, const float* __restrict__ el,
    const float* __restrict__ er, const float* __restrict__ M,
    const float* __restrict__ cvec, const int* __restrict__ row_ptr,
    const int* __restrict__ csr_src, float* __restrict__ out) {
  __shared__ float gs[4 * 4 * 256];
  int wave = threadIdx.x >> 6, lane = threadIdx.x & 63;
  int q = lane >> 4, r = lane & 15;
  int base = (blockIdx.x * 4 + wave) * 4;
  float* gw = &gs[wave * 1024];
#pragma unroll
  for (int t = 0; t < 4; ++t) {
    int n = __builtin_amdgcn_readfirstlane(base + t);
    Acc A;
    agg64(x, el, er, row_ptr, csr_src, n, q, r, A);
    float inv0 = A.s0 > 0.f ? 1.0f / A.s0 : 0.f;
    float inv1 = A.s1 > 0.f ? 1.0f / A.s1 : 0.f;
    float inv2 = A.s2 > 0.f ? 1.0f / A.s2 : 0.f;
    float inv3 = A.s3 > 0.f ? 1.0f / A.s3 : 0.f;
    float4 av = (q == 0) ? A.a0 : (q == 1) ? A.a1 : (q == 2) ? A.a2 : A.a3;
    float inv = (q == 0) ? inv0 : (q == 1) ? inv1 : (q == 2) ? inv2 : inv3;
    av.x *= inv; av.y *= inv; av.z *= inv; av.w *= inv;
    *(float4*)&gw[t * 256 + (q << 6) + (r << 2)] = av;
  }
  float y0 = 0.f, y1 = 0.f, y2 = 0.f, y3 = 0.f;
  for (int rr = 0; rr < 256; rr += 4) {
#pragma unroll
    for (int u = 0; u < 4; ++u) {
      int row = rr + u;
      float sv = M[(row << 6) + lane];
      float g0 = gw[0 * 256 + row], g1 = gw[1 * 256 + row];
      float g2 = gw[2 * 256 + row], g3 = gw[3 * 256 + row];
      y0 = fmaf(g0, sv, y0); y1 = fmaf(g1, sv, y1);
      y2 = fmaf(g2, sv, y2); y3 = fmaf(g3, sv, y3);
    }
  }
  float cl = cvec[lane];
  float ys[4] = {y0 + cl, y1 + cl, y2 + cl, y3 + cl};
#pragma unroll
  for (int t = 0; t < 4; ++t) {
    int n = base + t;
    float y = ys[t];
    float mu = wsum64(y) * (1.0f / 64.0f);
    float dv = y - mu;
    float var = wsum64(dv * dv) * (1.0f / 64.0f);
    out[(n << 6) + lane] = dv * rsqrtf(var + 1e-5f);
  }
}

// ---------------- launch ----------------
extern "C" void kernel_launch(void* const* d_in, const int* in_sizes, int n_in,
                              void* d_out, int out_size, void* d_ws, size_t ws_size,
                              hipStream_t stream) {
  const float* in_feat = (const float*)d_in[0];
  const int* src = (const int*)d_in[1];
  const int* dst = (const int*)d_in[2];
  const float* W1 = (const float*)d_in[3];
  const float* al1 = (const float*)d_in[4];
  const float* ar1 = (const float*)d_in[5];
  const float* b1 = (const float*)d_in[6];
  const float* Wh = (const float*)d_in[7];   // [3][64][256]
  const float* alh = (const float*)d_in[8];  // [3][4][64]
  const float* arh = (const float*)d_in[9];  // [3][4][64]
  const float* bh = (const float*)d_in[10];  // [3][256]
  const float* Wo = (const float*)d_in[11];  // [256][64]
  const float* bo = (const float*)d_in[12];  // [64]
  float* out = (float*)d_out;

  char* ws = (char*)d_ws;
  size_t off = 0;
  auto alloc = [&](size_t bytes) {
    void* p = ws + off;
    off = (off + bytes + 255) & ~(size_t)255;
    return p;
  };
  float* h_a = (float*)alloc((size_t)NN * 64 * 4);
  float* h_b = (float*)alloc((size_t)NN * 64 * 4);
  float* el_a = (float*)alloc((size_t)NN * 4 * 4);
  float* er_a = (float*)alloc((size_t)NN * 4 * 4);
  float* el_b = (float*)alloc((size_t)NN * 4 * 4);
  float* er_b = (float*)alloc((size_t)NN * 4 * 4);
  float* Q1 = (float*)alloc(128 * 8 * 4);
  float* Q2 = (float*)alloc(64 * 8 * 4);
  float* Q3 = (float*)alloc(64 * 8 * 4);
  float* Q4 = (float*)alloc(64 * 8 * 4);
  float* M = (float*)alloc(256 * 64 * 4);
  float* cvec = (float*)alloc(64 * 4);
  int* deg = (int*)alloc((size_t)NN * 4);
  int* row_ptr = (int*)alloc((size_t)(NN + 1) * 4);
  int* cursor = (int*)alloc((size_t)NN * 4);
  int* csr_src = (int*)alloc((size_t)NE * 4);
  (void)ws_size; (void)in_sizes; (void)n_in; (void)out_size;

  // CSR build
  zero_int_k<<<(NN + 255) / 256, 256, 0, stream>>>(deg, NN);
  count_deg_k<<<(NE + 255) / 256, 256, 0, stream>>>(dst, deg);
  scan_k<<<1, 1024, 0, stream>>>(deg, row_ptr, cursor);
  fill_csr_k<<<(NE + 255) / 256, 256, 0, stream>>>(src, dst, cursor, csr_src);

  // tiny precomputes
  compute_q_k<<<4, 256, 0, stream>>>(W1, al1, ar1, Q1, 128);
  compute_q_k<<<2, 256, 0, stream>>>(Wh + 0 * 64 * 256, alh + 0 * 256, arh + 0 * 256, Q2, 64);
  compute_q_k<<<2, 256, 0, stream>>>(Wh + 1 * 64 * 256, alh + 1 * 256, arh + 1 * 256, Q3, 64);
  compute_q_k<<<2, 256, 0, stream>>>(Wh + 2 * 64 * 256, alh + 2 * 256, arh + 2 * 256, Q4, 64);
  compute_m_k<<<256, 64, 0, stream>>>(Wh + 2 * 64 * 256, Wo, M);
  compute_c_k<<<1, 64, 0, stream>>>(bh + 2 * 256, Wo, bo, cvec);

  const int FUSED_GRID = NN / 16;  // 3125
  const int ELER_GRID = NN / 4;    // 12500

  // layer 1
  eler_k<128><<<ELER_GRID, 256, 0, stream>>>(in_feat, Q1, el_a, er_a);
  fused_l1_k<<<FUSED_GRID, 256, 0, stream>>>(in_feat, el_a, er_a, W1, b1, Q2,
                                             row_ptr, csr_src, h_a, el_b, er_b);
  // hidden layers
  fused_hidden_k<<<FUSED_GRID, 256, 0, stream>>>(h_a, el_b, er_b, Wh + 0 * 64 * 256,
                                                 bh + 0 * 256, Q3, row_ptr, csr_src,
                                                 h_b, el_a, er_a);
  fused_hidden_k<<<FUSED_GRID, 256, 0, stream>>>(h_b, el_a, er_a, Wh + 1 * 64 * 256,
                                                 bh + 1 * 256, Q4, row_ptr, csr_src,
                                                 h_a, el_b, er_b);
  // final layer + out_ln + LayerNorm
  fused_final_k<<<FUSED_GRID, 256, 0, stream>>>(h_a, el_b, er_b, M, cvec,
                                                row_ptr, csr_src, out);
}

// Round 5
// 658.300 us; speedup vs baseline: 1.7042x; 1.3063x over previous
//
#include <hip/hip_runtime.h>

#define NN 50000
#define NE 800000

// ---------------- wave helpers ----------------
__device__ __forceinline__ float wsum64(float v) {
#pragma unroll
  for (int off = 32; off; off >>= 1) v += __shfl_xor(v, off, 64);
  return v;
}
__device__ __forceinline__ float lrelu(float x) { return x > 0.0f ? x : 0.2f * x; }

// ---------------- CSR build ----------------
__global__ void zero_int_k(int* __restrict__ p, int n) {
  int i = blockIdx.x * 256 + threadIdx.x;
  if (i < n) p[i] = 0;
}

__global__ void count_deg_k(const int* __restrict__ dst, int* __restrict__ deg) {
  int e = blockIdx.x * 256 + threadIdx.x;
  if (e < NE) atomicAdd(&deg[dst[e]], 1);
}

__global__ __launch_bounds__(1024) void scan_k(const int* __restrict__ deg,
                                               int* __restrict__ row_ptr,
                                               int* __restrict__ cursor) {
  __shared__ int woff[16];
  int tid = threadIdx.x;
  int lane = tid & 63, wv = tid >> 6;
  const int CH = (NN + 1023) / 1024;  // 49
  int lo = tid * CH;
  int hi = lo + CH;
  if (lo > NN) lo = NN;
  if (hi > NN) hi = NN;
  int s = 0;
  for (int i = lo; i < hi; ++i) s += deg[i];
  int incl = s;
#pragma unroll
  for (int off = 1; off < 64; off <<= 1) {
    int t = __shfl_up(incl, off, 64);
    if (lane >= off) incl += t;
  }
  if (lane == 63) woff[wv] = incl;
  __syncthreads();
  if (tid == 0) {
    int run = 0;
#pragma unroll
    for (int w = 0; w < 16; ++w) { int t = woff[w]; woff[w] = run; run += t; }
    row_ptr[NN] = run;  // == NE
  }
  __syncthreads();
  int run = incl - s + woff[wv];
  for (int i = lo; i < hi; ++i) {
    row_ptr[i] = run;
    cursor[i] = run;
    run += deg[i];
  }
}

__global__ void fill_csr_k(const int* __restrict__ src, const int* __restrict__ dst,
                           int* __restrict__ cursor, int* __restrict__ csr_src) {
  int e = blockIdx.x * 256 + threadIdx.x;
  if (e < NE) {
    int pos = atomicAdd(&cursor[dst[e]], 1);
    csr_src[pos] = src[e];
  }
}

// ---------------- tiny precomputes ----------------
// Q[k][c], c<4 -> el proj head c, c>=4 -> er proj head c-4
__global__ void compute_q_k(const float* __restrict__ W, const float* __restrict__ al,
                            const float* __restrict__ ar, float* __restrict__ Q, int KDIM) {
  int idx = blockIdx.x * 256 + threadIdx.x;
  if (idx >= KDIM * 8) return;
  int k = idx >> 3, c = idx & 7;
  int h = c & 3;
  const float* av = (c < 4 ? al : ar) + h * 64;
  const float* wrow = W + (size_t)k * 256 + h * 64;
  float s = 0.0f;
  for (int m = 0; m < 64; ++m) s += wrow[m] * av[m];
  Q[idx] = s;
}

// M[(h*64+k)][d] = sum_j Wh2[k][h*64+j] * Wo[(h*64+j)][d]
__global__ void compute_m_k(const float* __restrict__ Wh2, const float* __restrict__ Wo,
                            float* __restrict__ M) {
  int row = blockIdx.x;  // 0..255
  int d = threadIdx.x;   // 0..63
  int h = row >> 6, k = row & 63;
  float s = 0.0f;
  for (int j = 0; j < 64; ++j)
    s += Wh2[k * 256 + h * 64 + j] * Wo[(h * 64 + j) * 64 + d];
  M[row * 64 + d] = s;
}

// cvec[d] = sum_m bh2[m]*Wo[m][d] + bo[d]
__global__ void compute_c_k(const float* __restrict__ bh2, const float* __restrict__ Wo,
                            const float* __restrict__ bo, float* __restrict__ cvec) {
  int d = threadIdx.x;
  if (d >= 64) return;
  float s = bo[d];
  for (int m = 0; m < 256; ++m) s += bh2[m] * Wo[m * 64 + d];
  cvec[d] = s;
}

// ---------------- el/er for layer 1 (from raw inputs) ----------------
__global__ __launch_bounds__(256) void eler_l1_k(const float* __restrict__ X,
                                                 const float* __restrict__ Q,
                                                 float* __restrict__ elp,
                                                 float* __restrict__ erp) {
  int n = __builtin_amdgcn_readfirstlane(blockIdx.x * 4 + (threadIdx.x >> 6));
  int lane = threadIdx.x & 63;
  float2 xv = *(const float2*)&X[(n << 7) + (lane << 1)];
  float4 qa0 = *(const float4*)&Q[(lane * 2) * 8];
  float4 qb0 = *(const float4*)&Q[(lane * 2) * 8 + 4];
  float4 qa1 = *(const float4*)&Q[(lane * 2 + 1) * 8];
  float4 qb1 = *(const float4*)&Q[(lane * 2 + 1) * 8 + 4];
  float p[8];
  p[0] = xv.x * qa0.x + xv.y * qa1.x; p[1] = xv.x * qa0.y + xv.y * qa1.y;
  p[2] = xv.x * qa0.z + xv.y * qa1.z; p[3] = xv.x * qa0.w + xv.y * qa1.w;
  p[4] = xv.x * qb0.x + xv.y * qb1.x; p[5] = xv.x * qb0.y + xv.y * qb1.y;
  p[6] = xv.x * qb0.z + xv.y * qb1.z; p[7] = xv.x * qb0.w + xv.y * qb1.w;
#pragma unroll
  for (int c = 0; c < 8; ++c) p[c] = wsum64(p[c]);
  if (lane == 0) {
    *(float4*)&elp[n << 2] = make_float4(p[0], p[1], p[2], p[3]);
    *(float4*)&erp[n << 2] = make_float4(p[4], p[5], p[6], p[7]);
  }
}

// ---------------- fused hidden layer ----------------
// Full wave per edge; lane (q=lane>>4, r=lane&15) owns head q, dims 4r..4r+3.
// acc = float4 + scalar denom per lane. No cross-lane reduction.
__global__ __launch_bounds__(256) void fused_hidden_k(
    const float* __restrict__ x, const float* __restrict__ el,
    const float* __restrict__ er, const float* __restrict__ W,
    const float* __restrict__ b, const float* __restrict__ Qn,
    const int* __restrict__ row_ptr, const int* __restrict__ csr_src,
    float* __restrict__ hout, float* __restrict__ eln, float* __restrict__ ern) {
  __shared__ float gs[4 * 4 * 256];
  int wave = threadIdx.x >> 6, lane = threadIdx.x & 63;
  int q = lane >> 4, r = lane & 15;
  int base = (blockIdx.x * 4 + wave) * 4;
  float* gw = &gs[wave * 1024];
  int r4 = r << 2;
#pragma unroll 1
  for (int t = 0; t < 4; ++t) {
    int n = __builtin_amdgcn_readfirstlane(base + t);
    int beg = row_ptr[n], end = row_ptr[n + 1];
    float erq = er[(n << 2) + q];
    float4 a = make_float4(0.f, 0.f, 0.f, 0.f);
    float sw = 0.f;
#define ESTEP(elv, xv)                      \
  do {                                      \
    float w = __expf(lrelu((elv) + erq));   \
    sw += w;                                \
    a.x = fmaf(w, (xv).x, a.x);             \
    a.y = fmaf(w, (xv).y, a.y);             \
    a.z = fmaf(w, (xv).z, a.z);             \
    a.w = fmaf(w, (xv).w, a.w);             \
  } while (0)
    int j = beg;
    for (; j + 8 <= end; j += 8) {
      int s0 = csr_src[j + 0], s1 = csr_src[j + 1];
      int s2 = csr_src[j + 2], s3 = csr_src[j + 3];
      int s4 = csr_src[j + 4], s5 = csr_src[j + 5];
      int s6 = csr_src[j + 6], s7 = csr_src[j + 7];
      float e0 = el[(s0 << 2) + q], e1 = el[(s1 << 2) + q];
      float e2 = el[(s2 << 2) + q], e3 = el[(s3 << 2) + q];
      float e4 = el[(s4 << 2) + q], e5 = el[(s5 << 2) + q];
      float e6 = el[(s6 << 2) + q], e7 = el[(s7 << 2) + q];
      float4 x0 = *(const float4*)&x[(s0 << 6) + r4];
      float4 x1 = *(const float4*)&x[(s1 << 6) + r4];
      float4 x2 = *(const float4*)&x[(s2 << 6) + r4];
      float4 x3 = *(const float4*)&x[(s3 << 6) + r4];
      float4 x4 = *(const float4*)&x[(s4 << 6) + r4];
      float4 x5 = *(const float4*)&x[(s5 << 6) + r4];
      float4 x6 = *(const float4*)&x[(s6 << 6) + r4];
      float4 x7 = *(const float4*)&x[(s7 << 6) + r4];
      ESTEP(e0, x0); ESTEP(e1, x1); ESTEP(e2, x2); ESTEP(e3, x3);
      ESTEP(e4, x4); ESTEP(e5, x5); ESTEP(e6, x6); ESTEP(e7, x7);
    }
    for (; j < end; ++j) {
      int s0 = csr_src[j];
      float e0 = el[(s0 << 2) + q];
      float4 x0 = *(const float4*)&x[(s0 << 6) + r4];
      ESTEP(e0, x0);
    }
#undef ESTEP
    float inv = sw > 0.f ? 1.0f / sw : 0.f;
    *(float4*)&gw[t * 256 + (q << 6) + r4] =
        make_float4(a.x * inv, a.y * inv, a.z * inv, a.w * inv);
  }
  // GEMV: y[t][lane] = sum_row g[t][row] * W[k][h*64+lane], row=h*64+k
  float y0 = 0.f, y1 = 0.f, y2 = 0.f, y3 = 0.f;
  for (int rr = 0; rr < 256; rr += 4) {
#pragma unroll
    for (int u = 0; u < 4; ++u) {
      int row = rr + u;
      int h = row >> 6, k = row & 63;
      float sv = W[k * 256 + (h << 6) + lane];
      y0 = fmaf(gw[0 * 256 + row], sv, y0);
      y1 = fmaf(gw[1 * 256 + row], sv, y1);
      y2 = fmaf(gw[2 * 256 + row], sv, y2);
      y3 = fmaf(gw[3 * 256 + row], sv, y3);
    }
  }
  float bsum = b[lane] + b[64 + lane] + b[128 + lane] + b[192 + lane];
  float4 qa = *(const float4*)&Qn[lane * 8];
  float4 qb = *(const float4*)&Qn[lane * 8 + 4];
  float ys[4] = {y0, y1, y2, y3};
#pragma unroll
  for (int t = 0; t < 4; ++t) {
    int n = base + t;
    float yv = 0.25f * (ys[t] + bsum);
    hout[(n << 6) + lane] = yv;
    float e0 = wsum64(yv * qa.x), e1 = wsum64(yv * qa.y);
    float e2 = wsum64(yv * qa.z), e3 = wsum64(yv * qa.w);
    float r0 = wsum64(yv * qb.x), r1 = wsum64(yv * qb.y);
    float r2 = wsum64(yv * qb.z), r3 = wsum64(yv * qb.w);
    if (lane == 0) {
      *(float4*)&eln[n << 2] = make_float4(e0, e1, e2, e3);
      *(float4*)&ern[n << 2] = make_float4(r0, r1, r2, r3);
    }
  }
}

// ---------------- fused layer 1 (in_feat dim 128) ----------------
// lane (q,r) owns head q, dims 8r..8r+7 (two float4s per edge).
__global__ __launch_bounds__(256) void fused_l1_k(
    const float* __restrict__ x, const float* __restrict__ el,
    const float* __restrict__ er, const float* __restrict__ W,
    const float* __restrict__ b, const float* __restrict__ Qn,
    const int* __restrict__ row_ptr, const int* __restrict__ csr_src,
    float* __restrict__ hout, float* __restrict__ eln, float* __restrict__ ern) {
  __shared__ float gs[4 * 4 * 512];
  int wave = threadIdx.x >> 6, lane = threadIdx.x & 63;
  int q = lane >> 4, r = lane & 15;
  int base = (blockIdx.x * 4 + wave) * 4;
  float* gw = &gs[wave * 2048];
  int r8 = r << 3;
#pragma unroll 1
  for (int t = 0; t < 4; ++t) {
    int n = __builtin_amdgcn_readfirstlane(base + t);
    int beg = row_ptr[n], end = row_ptr[n + 1];
    float erq = er[(n << 2) + q];
    float4 aA = make_float4(0.f, 0.f, 0.f, 0.f);
    float4 aB = make_float4(0.f, 0.f, 0.f, 0.f);
    float sw = 0.f;
#define ESTEP(elv, xa, xb)                  \
  do {                                      \
    float w = __expf(lrelu((elv) + erq));   \
    sw += w;                                \
    aA.x = fmaf(w, (xa).x, aA.x);           \
    aA.y = fmaf(w, (xa).y, aA.y);           \
    aA.z = fmaf(w, (xa).z, aA.z);           \
    aA.w = fmaf(w, (xa).w, aA.w);           \
    aB.x = fmaf(w, (xb).x, aB.x);           \
    aB.y = fmaf(w, (xb).y, aB.y);           \
    aB.z = fmaf(w, (xb).z, aB.z);           \
    aB.w = fmaf(w, (xb).w, aB.w);           \
  } while (0)
    int j = beg;
    for (; j + 4 <= end; j += 4) {
      int s0 = csr_src[j + 0], s1 = csr_src[j + 1];
      int s2 = csr_src[j + 2], s3 = csr_src[j + 3];
      float e0 = el[(s0 << 2) + q], e1 = el[(s1 << 2) + q];
      float e2 = el[(s2 << 2) + q], e3 = el[(s3 << 2) + q];
      float4 xa0 = *(const float4*)&x[(s0 << 7) + r8];
      float4 xb0 = *(const float4*)&x[(s0 << 7) + r8 + 4];
      float4 xa1 = *(const float4*)&x[(s1 << 7) + r8];
      float4 xb1 = *(const float4*)&x[(s1 << 7) + r8 + 4];
      float4 xa2 = *(const float4*)&x[(s2 << 7) + r8];
      float4 xb2 = *(const float4*)&x[(s2 << 7) + r8 + 4];
      float4 xa3 = *(const float4*)&x[(s3 << 7) + r8];
      float4 xb3 = *(const float4*)&x[(s3 << 7) + r8 + 4];
      ESTEP(e0, xa0, xb0); ESTEP(e1, xa1, xb1);
      ESTEP(e2, xa2, xb2); ESTEP(e3, xa3, xb3);
    }
    for (; j < end; ++j) {
      int s0 = csr_src[j];
      float e0 = el[(s0 << 2) + q];
      float4 xa0 = *(const float4*)&x[(s0 << 7) + r8];
      float4 xb0 = *(const float4*)&x[(s0 << 7) + r8 + 4];
      ESTEP(e0, xa0, xb0);
    }
#undef ESTEP
    float inv = sw > 0.f ? 1.0f / sw : 0.f;
    *(float4*)&gw[t * 512 + (q << 7) + r8] =
        make_float4(aA.x * inv, aA.y * inv, aA.z * inv, aA.w * inv);
    *(float4*)&gw[t * 512 + (q << 7) + r8 + 4] =
        make_float4(aB.x * inv, aB.y * inv, aB.z * inv, aB.w * inv);
  }
  // GEMV: row = h*128+k, sv = W[k*256 + h*64 + lane]
  float y0 = 0.f, y1 = 0.f, y2 = 0.f, y3 = 0.f;
  for (int rr = 0; rr < 512; rr += 4) {
#pragma unroll
    for (int u = 0; u < 4; ++u) {
      int row = rr + u;
      int h = row >> 7, k = row & 127;
      float sv = W[k * 256 + (h << 6) + lane];
      y0 = fmaf(gw[0 * 512 + row], sv, y0);
      y1 = fmaf(gw[1 * 512 + row], sv, y1);
      y2 = fmaf(gw[2 * 512 + row], sv, y2);
      y3 = fmaf(gw[3 * 512 + row], sv, y3);
    }
  }
  float bsum = b[lane] + b[64 + lane] + b[128 + lane] + b[192 + lane];
  float4 qa = *(const float4*)&Qn[lane * 8];
  float4 qb = *(const float4*)&Qn[lane * 8 + 4];
  float ys[4] = {y0, y1, y2, y3};
#pragma unroll
  for (int t = 0; t < 4; ++t) {
    int n = base + t;
    float yv = 0.25f * (ys[t] + bsum);
    hout[(n << 6) + lane] = yv;
    float e0 = wsum64(yv * qa.x), e1 = wsum64(yv * qa.y);
    float e2 = wsum64(yv * qa.z), e3 = wsum64(yv * qa.w);
    float r0 = wsum64(yv * qb.x), r1 = wsum64(yv * qb.y);
    float r2 = wsum64(yv * qb.z), r3 = wsum64(yv * qb.w);
    if (lane == 0) {
      *(float4*)&eln[n << 2] = make_float4(e0, e1, e2, e3);
      *(float4*)&ern[n << 2] = make_float4(r0, r1, r2, r3);
    }
  }
}

// ---------------- fused final: agg + GEMV(M) + cvec + LayerNorm ----------------
__global__ __launch_bounds__(256) void fused_final_k(
    const float* __restrict__ x, const float* __restrict__ el,
    const float* __restrict__ er, const float* __restrict__ M,
    const float* __restrict__ cvec, const int* __restrict__ row_ptr,
    const int* __restrict__ csr_src, float* __restrict__ out) {
  __shared__ float gs[4 * 4 * 256];
  int wave = threadIdx.x >> 6, lane = threadIdx.x & 63;
  int q = lane >> 4, r = lane & 15;
  int base = (blockIdx.x * 4 + wave) * 4;
  float* gw = &gs[wave * 1024];
  int r4 = r << 2;
#pragma unroll 1
  for (int t = 0; t < 4; ++t) {
    int n = __builtin_amdgcn_readfirstlane(base + t);
    int beg = row_ptr[n], end = row_ptr[n + 1];
    float erq = er[(n << 2) + q];
    float4 a = make_float4(0.f, 0.f, 0.f, 0.f);
    float sw = 0.f;
#define ESTEP(elv, xv)                      \
  do {                                      \
    float w = __expf(lrelu((elv) + erq));   \
    sw += w;                                \
    a.x = fmaf(w, (xv).x, a.x);             \
    a.y = fmaf(w, (xv).y, a.y);             \
    a.z = fmaf(w, (xv).z, a.z);             \
    a.w = fmaf(w, (xv).w, a.w);             \
  } while (0)
    int j = beg;
    for (; j + 8 <= end; j += 8) {
      int s0 = csr_src[j + 0], s1 = csr_src[j + 1];
      int s2 = csr_src[j + 2], s3 = csr_src[j + 3];
      int s4 = csr_src[j + 4], s5 = csr_src[j + 5];
      int s6 = csr_src[j + 6], s7 = csr_src[j + 7];
      float e0 = el[(s0 << 2) + q], e1 = el[(s1 << 2) + q];
      float e2 = el[(s2 << 2) + q], e3 = el[(s3 << 2) + q];
      float e4 = el[(s4 << 2) + q], e5 = el[(s5 << 2) + q];
      float e6 = el[(s6 << 2) + q], e7 = el[(s7 << 2) + q];
      float4 x0 = *(const float4*)&x[(s0 << 6) + r4];
      float4 x1 = *(const float4*)&x[(s1 << 6) + r4];
      float4 x2 = *(const float4*)&x[(s2 << 6) + r4];
      float4 x3 = *(const float4*)&x[(s3 << 6) + r4];
      float4 x4 = *(const float4*)&x[(s4 << 6) + r4];
      float4 x5 = *(const float4*)&x[(s5 << 6) + r4];
      float4 x6 = *(const float4*)&x[(s6 << 6) + r4];
      float4 x7 = *(const float4*)&x[(s7 << 6) + r4];
      ESTEP(e0, x0); ESTEP(e1, x1); ESTEP(e2, x2); ESTEP(e3, x3);
      ESTEP(e4, x4); ESTEP(e5, x5); ESTEP(e6, x6); ESTEP(e7, x7);
    }
    for (; j < end; ++j) {
      int s0 = csr_src[j];
      float e0 = el[(s0 << 2) + q];
      float4 x0 = *(const float4*)&x[(s0 << 6) + r4];
      ESTEP(e0, x0);
    }
#undef ESTEP
    float inv = sw > 0.f ? 1.0f / sw : 0.f;
    *(float4*)&gw[t * 256 + (q << 6) + r4] =
        make_float4(a.x * inv, a.y * inv, a.z * inv, a.w * inv);
  }
  float y0 = 0.f, y1 = 0.f, y2 = 0.f, y3 = 0.f;
  for (int rr = 0; rr < 256; rr += 4) {
#pragma unroll
    for (int u = 0; u < 4; ++u) {
      int row = rr + u;
      float sv = M[(row << 6) + lane];
      y0 = fmaf(gw[0 * 256 + row], sv, y0);
      y1 = fmaf(gw[1 * 256 + row], sv, y1);
      y2 = fmaf(gw[2 * 256 + row], sv, y2);
      y3 = fmaf(gw[3 * 256 + row], sv, y3);
    }
  }
  float cl = cvec[lane];
  float ys[4] = {y0 + cl, y1 + cl, y2 + cl, y3 + cl};
#pragma unroll
  for (int t = 0; t < 4; ++t) {
    int n = base + t;
    float y = ys[t];
    float mu = wsum64(y) * (1.0f / 64.0f);
    float dv = y - mu;
    float var = wsum64(dv * dv) * (1.0f / 64.0f);
    out[(n << 6) + lane] = dv * rsqrtf(var + 1e-5f);
  }
}

// ---------------- launch ----------------
extern "C" void kernel_launch(void* const* d_in, const int* in_sizes, int n_in,
                              void* d_out, int out_size, void* d_ws, size_t ws_size,
                              hipStream_t stream) {
  const float* in_feat = (const float*)d_in[0];
  const int* src = (const int*)d_in[1];
  const int* dst = (const int*)d_in[2];
  const float* W1 = (const float*)d_in[3];
  const float* al1 = (const float*)d_in[4];
  const float* ar1 = (const float*)d_in[5];
  const float* b1 = (const float*)d_in[6];
  const float* Wh = (const float*)d_in[7];   // [3][64][256]
  const float* alh = (const float*)d_in[8];  // [3][4][64]
  const float* arh = (const float*)d_in[9];  // [3][4][64]
  const float* bh = (const float*)d_in[10];  // [3][256]
  const float* Wo = (const float*)d_in[11];  // [256][64]
  const float* bo = (const float*)d_in[12];  // [64]
  float* out = (float*)d_out;

  char* ws = (char*)d_ws;
  size_t off = 0;
  auto alloc = [&](size_t bytes) {
    void* p = ws + off;
    off = (off + bytes + 255) & ~(size_t)255;
    return p;
  };
  float* h_a = (float*)alloc((size_t)NN * 64 * 4);
  float* h_b = (float*)alloc((size_t)NN * 64 * 4);
  float* el_a = (float*)alloc((size_t)NN * 4 * 4);
  float* er_a = (float*)alloc((size_t)NN * 4 * 4);
  float* el_b = (float*)alloc((size_t)NN * 4 * 4);
  float* er_b = (float*)alloc((size_t)NN * 4 * 4);
  float* Q1 = (float*)alloc(128 * 8 * 4);
  float* Q2 = (float*)alloc(64 * 8 * 4);
  float* Q3 = (float*)alloc(64 * 8 * 4);
  float* Q4 = (float*)alloc(64 * 8 * 4);
  float* M = (float*)alloc(256 * 64 * 4);
  float* cvec = (float*)alloc(64 * 4);
  int* deg = (int*)alloc((size_t)NN * 4);
  int* row_ptr = (int*)alloc((size_t)(NN + 1) * 4);
  int* cursor = (int*)alloc((size_t)NN * 4);
  int* csr_src = (int*)alloc((size_t)NE * 4);
  (void)ws_size; (void)in_sizes; (void)n_in; (void)out_size;

  // CSR build
  zero_int_k<<<(NN + 255) / 256, 256, 0, stream>>>(deg, NN);
  count_deg_k<<<(NE + 255) / 256, 256, 0, stream>>>(dst, deg);
  scan_k<<<1, 1024, 0, stream>>>(deg, row_ptr, cursor);
  fill_csr_k<<<(NE + 255) / 256, 256, 0, stream>>>(src, dst, cursor, csr_src);

  // tiny precomputes
  compute_q_k<<<4, 256, 0, stream>>>(W1, al1, ar1, Q1, 128);
  compute_q_k<<<2, 256, 0, stream>>>(Wh + 0 * 64 * 256, alh + 0 * 256, arh + 0 * 256, Q2, 64);
  compute_q_k<<<2, 256, 0, stream>>>(Wh + 1 * 64 * 256, alh + 1 * 256, arh + 1 * 256, Q3, 64);
  compute_q_k<<<2, 256, 0, stream>>>(Wh + 2 * 64 * 256, alh + 2 * 256, arh + 2 * 256, Q4, 64);
  compute_m_k<<<256, 64, 0, stream>>>(Wh + 2 * 64 * 256, Wo, M);
  compute_c_k<<<1, 64, 0, stream>>>(bh + 2 * 256, Wo, bo, cvec);

  const int FUSED_GRID = NN / 16;  // 3125
  const int ELER_GRID = NN / 4;    // 12500

  // layer 1
  eler_l1_k<<<ELER_GRID, 256, 0, stream>>>(in_feat, Q1, el_a, er_a);
  fused_l1_k<<<FUSED_GRID, 256, 0, stream>>>(in_feat, el_a, er_a, W1, b1, Q2,
                                             row_ptr, csr_src, h_a, el_b, er_b);
  // hidden layers
  fused_hidden_k<<<FUSED_GRID, 256, 0, stream>>>(h_a, el_b, er_b, Wh + 0 * 64 * 256,
                                                 bh + 0 * 256, Q3, row_ptr, csr_src,
                                                 h_b, el_a, er_a);
  fused_hidden_k<<<FUSED_GRID, 256, 0, stream>>>(h_b, el_a, er_a, Wh + 1 * 64 * 256,
                                                 bh + 1 * 256, Q4, row_ptr, csr_src,
                                                 h_a, el_b, er_b);
  // final layer + out_ln + LayerNorm
  fused_final_k<<<FUSED_GRID, 256, 0, stream>>>(h_a, el_b, er_b, M, cvec,
                                                row_ptr, csr_src, out);
}